// Round 5
// baseline (529.539 us; speedup 1.0000x reference)
//
#include <hip/hip_runtime.h>

#define D 64
#define RB 1024           // rows per bucket (pow2)
#define RB_SHIFT 10
#define COL_BITS 19
#define COL_MASK ((1u << COL_BITS) - 1u)

// ============================ common small kernels ==========================

__global__ __launch_bounds__(256) void k_gather_init(
    const float* __restrict__ uw, const float* __restrict__ iw,
    const int* __restrict__ ui, const int* __restrict__ ii,
    float* __restrict__ out, int nq)
{
    int t = blockIdx.x * 256 + threadIdx.x;
    int total = nq * D;
    if (t < total) {
        int q = t >> 6, d = t & 63;
        out[t] = uw[ui[q] * D + d];
    } else if (t < 2 * total) {
        int u = t - total;
        int q = u >> 6, d = u & 63;
        out[t] = iw[ii[q] * D + d];
    }
}

__global__ __launch_bounds__(256) void k_gather_acc(
    const float* __restrict__ src,
    const int* __restrict__ ui, const int* __restrict__ ii,
    int n_users, float* __restrict__ out, int nq, float scale)
{
    int t = blockIdx.x * 256 + threadIdx.x;
    int total = nq * D;
    if (t < total) {
        int q = t >> 6, d = t & 63;
        int node = ui[q];
        out[t] = (out[t] + src[node * D + d]) * scale;
    } else if (t < 2 * total) {
        int u = t - total;
        int q = u >> 6, d = u & 63;
        int node = n_users + ii[q];
        out[t] = (out[t] + src[node * D + d]) * scale;
    }
}

// ============================== CSR build ===================================

__global__ __launch_bounds__(256) void k_count(
    const int* __restrict__ rows, int* __restrict__ cnt, int ne)
{
    int e = blockIdx.x * 256 + threadIdx.x;
    if (e < ne) atomicAdd(&cnt[rows[e]], 1);
}

__global__ __launch_bounds__(1024) void k_scan1(
    const int* __restrict__ cnt, int* __restrict__ rstart,
    int* __restrict__ bsum, int n)
{
    __shared__ int s[1024];
    int t = threadIdx.x, i = blockIdx.x * 1024 + t;
    int v = (i < n) ? cnt[i] : 0;
    s[t] = v; __syncthreads();
    for (int off = 1; off < 1024; off <<= 1) {
        int x = (t >= off) ? s[t - off] : 0;
        __syncthreads();
        s[t] += x;
        __syncthreads();
    }
    if (i < n) rstart[i] = s[t] - v;
    if (t == 1023) bsum[blockIdx.x] = s[t];
}

__global__ __launch_bounds__(1024) void k_scan2(int* __restrict__ bsum, int nb)
{
    __shared__ int s[1024];
    int t = threadIdx.x;
    int v = (t < nb) ? bsum[t] : 0;
    s[t] = v; __syncthreads();
    for (int off = 1; off < 1024; off <<= 1) {
        int x = (t >= off) ? s[t - off] : 0;
        __syncthreads();
        s[t] += x;
        __syncthreads();
    }
    if (t < nb) bsum[t] = s[t] - v;
}

// finalize: rstart += block base; fill (scatter cursor) = rstart;
// bucketFill[b] = rstart[b*RB] (bucket append cursor)
__global__ __launch_bounds__(1024) void k_scan3(
    int* __restrict__ rstart, int* __restrict__ fill,
    const int* __restrict__ bsum, int* __restrict__ bucketFill, int n)
{
    int i = blockIdx.x * 1024 + threadIdx.x;
    if (i < n) {
        int v = rstart[i] + bsum[blockIdx.x];
        rstart[i] = v;
        fill[i] = v;
        if ((i & (RB - 1)) == 0) bucketFill[i >> RB_SHIFT] = v;
    }
}

// ---- stage B: partition edges into row-buckets (bucket-major staging) ----
// staging[p] = { (localrow<<19)|col , val }
#define TILE 2048
__global__ __launch_bounds__(256) void k_binpart(
    const float* __restrict__ vals, const int* __restrict__ rows,
    const int* __restrict__ cols,
    int* __restrict__ bucketFill, int2* __restrict__ staging,
    int ne, int nb)
{
    __shared__ int shist[512];   // per-block bucket histogram, then reused
    __shared__ int sgb[512];     // per-block global base per bucket
    int tid = threadIdx.x;
    int base = blockIdx.x * TILE;

    for (int b = tid; b < nb; b += 256) shist[b] = 0;
    __syncthreads();

    int myb[TILE / 256];
    int myr[TILE / 256];
    // count
    for (int k = 0; k < TILE / 256; ++k) {
        int e = base + k * 256 + tid;
        int b = -1, r = 0;
        if (e < ne) {
            r = rows[e];
            b = r >> RB_SHIFT;
            atomicAdd(&shist[b], 1);
        }
        myb[k] = b; myr[k] = r;
    }
    __syncthreads();
    // reserve global ranges, reset local cursors
    for (int b = tid; b < nb; b += 256) {
        int c = shist[b];
        sgb[b] = (c > 0) ? atomicAdd(&bucketFill[b], c) : 0;
        shist[b] = 0;
    }
    __syncthreads();
    // write packed edges
    for (int k = 0; k < TILE / 256; ++k) {
        int e = base + k * 256 + tid;
        if (e >= ne) continue;
        int b = myb[k];
        int lofs = atomicAdd(&shist[b], 1);
        int2 pk;
        pk.x = (int)((((unsigned)myr[k] & (RB - 1)) << COL_BITS) | (unsigned)cols[e]);
        pk.y = __float_as_int(vals[e]);
        staging[sgb[b] + lofs] = pk;
    }
}

// ---- stage C: exact placement within each bucket's L2-resident window ----
// grid = 2*nb blocks; block (b,h) handles half of bucket b's staged edges.
__global__ __launch_bounds__(256) void k_place(
    const int* __restrict__ rstart, const int2* __restrict__ staging,
    int* __restrict__ fill, int2* __restrict__ cedge, int n_nodes, int ne)
{
    int b = blockIdx.x >> 1;
    int h = blockIdx.x & 1;
    int rowbase = b << RB_SHIFT;
    int s = rstart[rowbase];
    int next = rowbase + RB;
    int e = (next < n_nodes) ? rstart[next] : ne;
    int cnt = e - s;
    int half = (cnt + 1) >> 1;
    int lo = s + h * half;
    int hi = (h == 0) ? (s + half) : e;
    for (int p = lo + threadIdx.x; p < hi; p += 256) {
        int2 pk = staging[p];
        int lr = ((unsigned)pk.x) >> COL_BITS;
        int r = rowbase + lr;
        int pos = atomicAdd(&fill[r], 1);
        int2 outp;
        outp.x = (int)((unsigned)pk.x & COL_MASK);
        outp.y = pk.y;
        cedge[pos] = outp;
    }
}

// mark nodes whose layer-2 value is needed: Q itself and neighbors(Q)
__global__ __launch_bounds__(256) void k_mark(
    const int* __restrict__ rstart, const int* __restrict__ cnt,
    const int2* __restrict__ cedge,
    const int* __restrict__ ui, const int* __restrict__ ii,
    int n_users, unsigned char* __restrict__ flag, int nq)
{
    int q = blockIdx.x * 256 + threadIdx.x;
    if (q >= 2 * nq) return;
    int node = (q < nq) ? ui[q] : n_users + ii[q - nq];
    flag[node] = 1;
    int s = rstart[node], dg = cnt[node];
    for (int j = 0; j < dg; ++j) flag[cedge[s + j].x] = 1;
}

// ============================== CSR SpMM ====================================
__global__ __launch_bounds__(256) void k_spmm_csr(
    const int* __restrict__ rstart, const int* __restrict__ cnt,
    const int2* __restrict__ cedge,
    const float* __restrict__ srcu, const float* __restrict__ srci,
    int n_users, float* __restrict__ dst, int n_nodes,
    const unsigned char* __restrict__ flag)
{
    int lane16 = threadIdx.x & 15;
    int row = blockIdx.x * 16 + (threadIdx.x >> 4);
    if (row >= n_nodes) return;
    if (flag && !flag[row]) return;

    int s = rstart[row], dg = cnt[row];
    float4 a0 = {0, 0, 0, 0}, a1 = {0, 0, 0, 0};
    int j = 0;
    for (; j + 1 < dg; j += 2) {
        int2 e0 = cedge[s + j], e1 = cedge[s + j + 1];
        int   c0 = e0.x,                 c1 = e1.x;
        float v0 = __int_as_float(e0.y), v1 = __int_as_float(e1.y);
        const float* p0 = (c0 < n_users) ? &srcu[(size_t)c0 * D] : &srci[(size_t)(c0 - n_users) * D];
        const float* p1 = (c1 < n_users) ? &srcu[(size_t)c1 * D] : &srci[(size_t)(c1 - n_users) * D];
        float4 x0 = ((const float4*)p0)[lane16];
        float4 x1 = ((const float4*)p1)[lane16];
        a0.x += v0 * x0.x; a0.y += v0 * x0.y; a0.z += v0 * x0.z; a0.w += v0 * x0.w;
        a1.x += v1 * x1.x; a1.y += v1 * x1.y; a1.z += v1 * x1.z; a1.w += v1 * x1.w;
    }
    if (j < dg) {
        int2 e0 = cedge[s + j];
        int c0 = e0.x; float v0 = __int_as_float(e0.y);
        const float* p0 = (c0 < n_users) ? &srcu[(size_t)c0 * D] : &srci[(size_t)(c0 - n_users) * D];
        float4 x0 = ((const float4*)p0)[lane16];
        a0.x += v0 * x0.x; a0.y += v0 * x0.y; a0.z += v0 * x0.z; a0.w += v0 * x0.w;
    }
    a0.x += a1.x; a0.y += a1.y; a0.z += a1.z; a0.w += a1.w;
    ((float4*)&dst[(size_t)row * D])[lane16] = a0;
}

// ======================= layer-3: per-query CSR walk ========================
__global__ __launch_bounds__(256) void k_final(
    const int* __restrict__ rstart, const int* __restrict__ cnt,
    const int2* __restrict__ cedge,
    const float* __restrict__ src,
    const int* __restrict__ ui, const int* __restrict__ ii,
    int n_users, float* __restrict__ out, int nq, float scale)
{
    int lane16 = threadIdx.x & 15;
    int q = blockIdx.x * 16 + (threadIdx.x >> 4);
    if (q >= 2 * nq) return;
    int node = (q < nq) ? ui[q] : n_users + ii[q - nq];

    int s = rstart[node], dg = cnt[node];
    float4 a0 = ((const float4*)&out[(size_t)q * D])[lane16];
    for (int j = 0; j < dg; ++j) {
        int2 e = cedge[s + j];
        int c = e.x; float v = __int_as_float(e.y);
        float4 x = ((const float4*)&src[(size_t)c * D])[lane16];
        a0.x += v * x.x; a0.y += v * x.y; a0.z += v * x.z; a0.w += v * x.w;
    }
    a0.x *= scale; a0.y *= scale; a0.z *= scale; a0.w *= scale;
    ((float4*)&out[(size_t)q * D])[lane16] = a0;
}

// ===================== fallback (atomic path) ===============================

__global__ __launch_bounds__(256) void k_spmm_l0(
    const float* __restrict__ vals, const int* __restrict__ rows,
    const int* __restrict__ cols,
    const float* __restrict__ uw, const float* __restrict__ iw, int n_users,
    float* __restrict__ dst, int n_edges)
{
    int total = n_edges * D;
    int stride = gridDim.x * 256;
    for (int t = blockIdx.x * 256 + threadIdx.x; t < total; t += stride) {
        int e = t >> 6, d = t & 63;
        float v = vals[e];
        int c = cols[e], r = rows[e];
        float x = (c < n_users) ? uw[c * D + d] : iw[(c - n_users) * D + d];
        atomicAdd(dst + r * D + d, v * x);
    }
}

__global__ __launch_bounds__(256) void k_spmm(
    const float* __restrict__ vals, const int* __restrict__ rows,
    const int* __restrict__ cols,
    const float* __restrict__ src, float* __restrict__ dst, int n_edges)
{
    int total = n_edges * D;
    int stride = gridDim.x * 256;
    for (int t = blockIdx.x * 256 + threadIdx.x; t < total; t += stride) {
        int e = t >> 6, d = t & 63;
        float v = vals[e];
        int c = cols[e], r = rows[e];
        atomicAdd(dst + r * D + d, v * src[c * D + d]);
    }
}

// ============================================================================

extern "C" void kernel_launch(void* const* d_in, const int* in_sizes, int n_in,
                              void* d_out, int out_size, void* d_ws, size_t ws_size,
                              hipStream_t stream) {
    const float* uw   = (const float*)d_in[0];
    const float* iw   = (const float*)d_in[1];
    const float* vals = (const float*)d_in[2];
    const int*   rows = (const int*)d_in[3];
    const int*   cols = (const int*)d_in[4];
    const int*   ui   = (const int*)d_in[5];
    const int*   ii   = (const int*)d_in[6];
    float* out = (float*)d_out;

    const int n_users = in_sizes[0] / D;
    const int n_items = in_sizes[1] / D;
    const int n_nodes = n_users + n_items;
    const int n_edges = in_sizes[2];
    const int nq      = in_sizes[5];

    const size_t buf_elems = (size_t)n_nodes * D;
    const int nb = (n_nodes + RB - 1) / RB;          // row buckets

    // ---- workspace carve ----
    size_t off = 0;
    float* bufA    = (float*)((char*)d_ws + off); off += buf_elems * 4;
    float* bufB    = (float*)((char*)d_ws + off); off += buf_elems * 4;
    int*   cnt     = (int*)  ((char*)d_ws + off); off += (size_t)n_nodes * 4;
    int*   rstart  = (int*)  ((char*)d_ws + off); off += (size_t)n_nodes * 4;
    int*   fill    = (int*)  ((char*)d_ws + off); off += (size_t)n_nodes * 4;
    int*   bsum    = (int*)  ((char*)d_ws + off); off += 4096 * 4;
    int*   bktFill = (int*)  ((char*)d_ws + off); off += 4096 * 4;
    unsigned char* flag = (unsigned char*)((char*)d_ws + off);
    off += ((size_t)n_nodes + 255) & ~(size_t)255;
    int2*  cedge   = (int2*) ((char*)d_ws + off); off += (size_t)n_edges * 8;
    int2*  staging = (int2*) ((char*)d_ws + off); off += (size_t)n_edges * 8;

    const int nblk_scan = (n_nodes + 1023) / 1024;
    const int gq = (2 * nq * D + 255) / 256;
    const bool csr_ok = (off <= ws_size) && (nblk_scan <= 1024) &&
                        (nb <= 512) && (n_nodes < (1 << COL_BITS));

    if (csr_ok) {
        // ---- CSR build ----
        hipMemsetAsync(cnt, 0, (size_t)n_nodes * 4, stream);
        hipMemsetAsync(flag, 0, (size_t)n_nodes, stream);
        k_count<<<(n_edges + 255) / 256, 256, 0, stream>>>(rows, cnt, n_edges);
        k_scan1<<<nblk_scan, 1024, 0, stream>>>(cnt, rstart, bsum, n_nodes);
        k_scan2<<<1, 1024, 0, stream>>>(bsum, nblk_scan);
        k_scan3<<<nblk_scan, 1024, 0, stream>>>(rstart, fill, bsum, bktFill, n_nodes);
        k_binpart<<<(n_edges + TILE - 1) / TILE, 256, 0, stream>>>(
            vals, rows, cols, bktFill, staging, n_edges, nb);
        k_place<<<2 * nb, 256, 0, stream>>>(rstart, staging, fill, cedge, n_nodes, n_edges);

        // mark nodes whose layer-2 output is actually consumed
        k_mark<<<(2 * nq + 255) / 256, 256, 0, stream>>>(
            rstart, cnt, cedge, ui, ii, n_users, flag, nq);

        // ---- layer 0 gather ----
        k_gather_init<<<gq, 256, 0, stream>>>(uw, iw, ui, ii, out, nq);

        const int gs = (n_nodes + 15) / 16;
        // ---- layer 1: emb -> bufA (all rows) ----
        k_spmm_csr<<<gs, 256, 0, stream>>>(rstart, cnt, cedge,
                                           uw, iw, n_users, bufA, n_nodes, nullptr);
        k_gather_acc<<<gq, 256, 0, stream>>>(bufA, ui, ii, n_users, out, nq, 1.0f);

        // ---- layer 2: bufA -> bufB (marked rows only) ----
        k_spmm_csr<<<gs, 256, 0, stream>>>(rstart, cnt, cedge,
                                           bufA, bufA + (size_t)n_users * D,
                                           n_users, bufB, n_nodes, flag);
        k_gather_acc<<<gq, 256, 0, stream>>>(bufB, ui, ii, n_users, out, nq, 1.0f);

        // ---- layer 3: per-query only ----
        k_final<<<(2 * nq + 15) / 16, 256, 0, stream>>>(
            rstart, cnt, cedge, bufB, ui, ii, n_users, out, nq, 0.25f);
    } else {
        // ---- fallback: atomic path ----
        hipMemsetAsync(bufA, 0, 2 * buf_elems * 4, stream);
        const int gs = 8192;
        k_gather_init<<<gq, 256, 0, stream>>>(uw, iw, ui, ii, out, nq);
        k_spmm_l0<<<gs, 256, 0, stream>>>(vals, rows, cols, uw, iw, n_users, bufA, n_edges);
        k_gather_acc<<<gq, 256, 0, stream>>>(bufA, ui, ii, n_users, out, nq, 1.0f);
        k_spmm<<<gs, 256, 0, stream>>>(vals, rows, cols, bufA, bufB, n_edges);
        k_gather_acc<<<gq, 256, 0, stream>>>(bufB, ui, ii, n_users, out, nq, 1.0f);
        hipMemsetAsync(bufA, 0, buf_elems * 4, stream);
        k_spmm<<<gs, 256, 0, stream>>>(vals, rows, cols, bufB, bufA, n_edges);
        k_gather_acc<<<gq, 256, 0, stream>>>(bufA, ui, ii, n_users, out, nq, 0.25f);
    }
}

// Round 6
// 447.469 us; speedup vs baseline: 1.1834x; 1.1834x over previous
//
#include <hip/hip_runtime.h>

#define D 64
#define RB 512            // rows per bucket (pow2)
#define RB_SHIFT 9
#define COL_BITS 19
#define COL_MASK ((1u << COL_BITS) - 1u)
#define CAP 4096          // max staged edges per bucket held in LDS
#define NBMAX 640         // max buckets supported by k_binpart LDS arrays
#define TILE 4096         // edges per k_binpart block

// ============================ common small kernels ==========================

__global__ __launch_bounds__(256) void k_gather_init(
    const float* __restrict__ uw, const float* __restrict__ iw,
    const int* __restrict__ ui, const int* __restrict__ ii,
    float* __restrict__ out, int nq)
{
    int t = blockIdx.x * 256 + threadIdx.x;
    int total = nq * D;
    if (t < total) {
        int q = t >> 6, d = t & 63;
        out[t] = uw[ui[q] * D + d];
    } else if (t < 2 * total) {
        int u = t - total;
        int q = u >> 6, d = u & 63;
        out[t] = iw[ii[q] * D + d];
    }
}

__global__ __launch_bounds__(256) void k_gather_acc(
    const float* __restrict__ src,
    const int* __restrict__ ui, const int* __restrict__ ii,
    int n_users, float* __restrict__ out, int nq, float scale)
{
    int t = blockIdx.x * 256 + threadIdx.x;
    int total = nq * D;
    if (t < total) {
        int q = t >> 6, d = t & 63;
        int node = ui[q];
        out[t] = (out[t] + src[node * D + d]) * scale;
    } else if (t < 2 * total) {
        int u = t - total;
        int q = u >> 6, d = u & 63;
        int node = n_users + ii[q];
        out[t] = (out[t] + src[node * D + d]) * scale;
    }
}

// ============================== CSR build ===================================

__global__ __launch_bounds__(256) void k_count(
    const int* __restrict__ rows, int* __restrict__ cnt, int ne)
{
    int e = blockIdx.x * 256 + threadIdx.x;
    if (e < ne) atomicAdd(&cnt[rows[e]], 1);
}

__global__ __launch_bounds__(1024) void k_scan1(
    const int* __restrict__ cnt, int* __restrict__ rstart,
    int* __restrict__ bsum, int n)
{
    __shared__ int s[1024];
    int t = threadIdx.x, i = blockIdx.x * 1024 + t;
    int v = (i < n) ? cnt[i] : 0;
    s[t] = v; __syncthreads();
    for (int off = 1; off < 1024; off <<= 1) {
        int x = (t >= off) ? s[t - off] : 0;
        __syncthreads();
        s[t] += x;
        __syncthreads();
    }
    if (i < n) rstart[i] = s[t] - v;
    if (t == 1023) bsum[blockIdx.x] = s[t];
}

__global__ __launch_bounds__(1024) void k_scan2(int* __restrict__ bsum, int nb)
{
    __shared__ int s[1024];
    int t = threadIdx.x;
    int v = (t < nb) ? bsum[t] : 0;
    s[t] = v; __syncthreads();
    for (int off = 1; off < 1024; off <<= 1) {
        int x = (t >= off) ? s[t - off] : 0;
        __syncthreads();
        s[t] += x;
        __syncthreads();
    }
    if (t < nb) bsum[t] = s[t] - v;
}

// finalize: rstart += block base; fill = rstart (overflow-path cursors);
// bucketFill[b] = rstart[b*RB] (bucket append cursor for binpart)
__global__ __launch_bounds__(1024) void k_scan3(
    int* __restrict__ rstart, int* __restrict__ fill,
    const int* __restrict__ bsum, int* __restrict__ bucketFill, int n)
{
    int i = blockIdx.x * 1024 + threadIdx.x;
    if (i < n) {
        int v = rstart[i] + bsum[blockIdx.x];
        rstart[i] = v;
        fill[i] = v;
        if ((i & (RB - 1)) == 0) bucketFill[i >> RB_SHIFT] = v;
    }
}

// ---- stage B: partition edges into row-buckets (bucket-major staging) ----
// staging[p] = { (localrow<<COL_BITS)|col , val }
__global__ __launch_bounds__(256) void k_binpart(
    const float* __restrict__ vals, const int* __restrict__ rows,
    const int* __restrict__ cols,
    int* __restrict__ bucketFill, int2* __restrict__ staging,
    int ne, int nb)
{
    __shared__ int shist[NBMAX];
    __shared__ int sgb[NBMAX];
    int tid = threadIdx.x;
    int base = blockIdx.x * TILE;

    for (int b = tid; b < nb; b += 256) shist[b] = 0;
    __syncthreads();

    int myb[TILE / 256];
    int myr[TILE / 256];
    for (int k = 0; k < TILE / 256; ++k) {
        int e = base + k * 256 + tid;
        int b = -1, r = 0;
        if (e < ne) {
            r = rows[e];
            b = r >> RB_SHIFT;
            atomicAdd(&shist[b], 1);
        }
        myb[k] = b; myr[k] = r;
    }
    __syncthreads();
    for (int b = tid; b < nb; b += 256) {
        int c = shist[b];
        sgb[b] = (c > 0) ? atomicAdd(&bucketFill[b], c) : 0;
        shist[b] = 0;
    }
    __syncthreads();
    for (int k = 0; k < TILE / 256; ++k) {
        int e = base + k * 256 + tid;
        if (e >= ne) continue;
        int b = myb[k];
        int lofs = atomicAdd(&shist[b], 1);
        int2 pk;
        pk.x = (int)((((unsigned)myr[k] & (RB - 1)) << COL_BITS) | (unsigned)cols[e]);
        pk.y = __float_as_int(vals[e]);
        staging[sgb[b] + lofs] = pk;
    }
}

// ---- stage C: within-bucket ordering in LDS, coalesced stream-out ----
__global__ __launch_bounds__(256) void k_place2(
    const int* __restrict__ rstart, const int2* __restrict__ staging,
    int* __restrict__ fill, int2* __restrict__ cedge, int n_nodes, int ne)
{
    __shared__ int cursor[RB];
    __shared__ int2 ebuf[CAP];
    int b = blockIdx.x;
    int rowbase = b << RB_SHIFT;
    int s = rstart[rowbase];
    int nextrow = rowbase + RB;
    int e = (nextrow < n_nodes) ? rstart[nextrow] : ne;
    int cnt = e - s;

    if (cnt <= CAP) {
        for (int i = threadIdx.x; i < RB; i += 256) {
            int r = rowbase + i;
            cursor[i] = ((r < n_nodes) ? rstart[r] : ne) - s;
        }
        __syncthreads();
        for (int p = s + threadIdx.x; p < e; p += 256) {
            int2 pk = staging[p];
            int lr = ((unsigned)pk.x) >> COL_BITS;
            int pos = atomicAdd(&cursor[lr], 1);
            pk.x = (int)((unsigned)pk.x & COL_MASK);
            ebuf[pos] = pk;
        }
        __syncthreads();
        for (int p = threadIdx.x; p < cnt; p += 256)
            cedge[s + p] = ebuf[p];
    } else {
        // overflow fallback (statistically unreachable): global cursors
        for (int p = s + threadIdx.x; p < e; p += 256) {
            int2 pk = staging[p];
            int lr = ((unsigned)pk.x) >> COL_BITS;
            int r = rowbase + lr;
            int pos = atomicAdd(&fill[r], 1);
            pk.x = (int)((unsigned)pk.x & COL_MASK);
            cedge[pos] = pk;
        }
    }
}

// mark nodes whose layer-2 value is needed: Q itself and neighbors(Q)
__global__ __launch_bounds__(256) void k_mark(
    const int* __restrict__ rstart, const int* __restrict__ cnt,
    const int2* __restrict__ cedge,
    const int* __restrict__ ui, const int* __restrict__ ii,
    int n_users, unsigned char* __restrict__ flag, int nq)
{
    int q = blockIdx.x * 256 + threadIdx.x;
    if (q >= 2 * nq) return;
    int node = (q < nq) ? ui[q] : n_users + ii[q - nq];
    flag[node] = 1;
    int s = rstart[node], dg = cnt[node];
    for (int j = 0; j < dg; ++j) flag[cedge[s + j].x] = 1;
}

// ============================== CSR SpMM ====================================
__global__ __launch_bounds__(256) void k_spmm_csr(
    const int* __restrict__ rstart, const int* __restrict__ cnt,
    const int2* __restrict__ cedge,
    const float* __restrict__ srcu, const float* __restrict__ srci,
    int n_users, float* __restrict__ dst, int n_nodes,
    const unsigned char* __restrict__ flag)
{
    int lane16 = threadIdx.x & 15;
    int row = blockIdx.x * 16 + (threadIdx.x >> 4);
    if (row >= n_nodes) return;
    if (flag && !flag[row]) return;

    int s = rstart[row], dg = cnt[row];
    float4 a0 = {0, 0, 0, 0}, a1 = {0, 0, 0, 0};
    int j = 0;
    for (; j + 1 < dg; j += 2) {
        int2 e0 = cedge[s + j], e1 = cedge[s + j + 1];
        int   c0 = e0.x,                 c1 = e1.x;
        float v0 = __int_as_float(e0.y), v1 = __int_as_float(e1.y);
        const float* p0 = (c0 < n_users) ? &srcu[(size_t)c0 * D] : &srci[(size_t)(c0 - n_users) * D];
        const float* p1 = (c1 < n_users) ? &srcu[(size_t)c1 * D] : &srci[(size_t)(c1 - n_users) * D];
        float4 x0 = ((const float4*)p0)[lane16];
        float4 x1 = ((const float4*)p1)[lane16];
        a0.x += v0 * x0.x; a0.y += v0 * x0.y; a0.z += v0 * x0.z; a0.w += v0 * x0.w;
        a1.x += v1 * x1.x; a1.y += v1 * x1.y; a1.z += v1 * x1.z; a1.w += v1 * x1.w;
    }
    if (j < dg) {
        int2 e0 = cedge[s + j];
        int c0 = e0.x; float v0 = __int_as_float(e0.y);
        const float* p0 = (c0 < n_users) ? &srcu[(size_t)c0 * D] : &srci[(size_t)(c0 - n_users) * D];
        float4 x0 = ((const float4*)p0)[lane16];
        a0.x += v0 * x0.x; a0.y += v0 * x0.y; a0.z += v0 * x0.z; a0.w += v0 * x0.w;
    }
    a0.x += a1.x; a0.y += a1.y; a0.z += a1.z; a0.w += a1.w;
    ((float4*)&dst[(size_t)row * D])[lane16] = a0;
}

// ======================= layer-3: per-query CSR walk ========================
__global__ __launch_bounds__(256) void k_final(
    const int* __restrict__ rstart, const int* __restrict__ cnt,
    const int2* __restrict__ cedge,
    const float* __restrict__ src,
    const int* __restrict__ ui, const int* __restrict__ ii,
    int n_users, float* __restrict__ out, int nq, float scale)
{
    int lane16 = threadIdx.x & 15;
    int q = blockIdx.x * 16 + (threadIdx.x >> 4);
    if (q >= 2 * nq) return;
    int node = (q < nq) ? ui[q] : n_users + ii[q - nq];

    int s = rstart[node], dg = cnt[node];
    float4 a0 = ((const float4*)&out[(size_t)q * D])[lane16];
    for (int j = 0; j < dg; ++j) {
        int2 e = cedge[s + j];
        int c = e.x; float v = __int_as_float(e.y);
        float4 x = ((const float4*)&src[(size_t)c * D])[lane16];
        a0.x += v * x.x; a0.y += v * x.y; a0.z += v * x.z; a0.w += v * x.w;
    }
    a0.x *= scale; a0.y *= scale; a0.z *= scale; a0.w *= scale;
    ((float4*)&out[(size_t)q * D])[lane16] = a0;
}

// ===================== fallback (atomic path) ===============================

__global__ __launch_bounds__(256) void k_spmm_l0(
    const float* __restrict__ vals, const int* __restrict__ rows,
    const int* __restrict__ cols,
    const float* __restrict__ uw, const float* __restrict__ iw, int n_users,
    float* __restrict__ dst, int n_edges)
{
    int total = n_edges * D;
    int stride = gridDim.x * 256;
    for (int t = blockIdx.x * 256 + threadIdx.x; t < total; t += stride) {
        int e = t >> 6, d = t & 63;
        float v = vals[e];
        int c = cols[e], r = rows[e];
        float x = (c < n_users) ? uw[c * D + d] : iw[(c - n_users) * D + d];
        atomicAdd(dst + r * D + d, v * x);
    }
}

__global__ __launch_bounds__(256) void k_spmm(
    const float* __restrict__ vals, const int* __restrict__ rows,
    const int* __restrict__ cols,
    const float* __restrict__ src, float* __restrict__ dst, int n_edges)
{
    int total = n_edges * D;
    int stride = gridDim.x * 256;
    for (int t = blockIdx.x * 256 + threadIdx.x; t < total; t += stride) {
        int e = t >> 6, d = t & 63;
        float v = vals[e];
        int c = cols[e], r = rows[e];
        atomicAdd(dst + r * D + d, v * src[c * D + d]);
    }
}

// ============================================================================

extern "C" void kernel_launch(void* const* d_in, const int* in_sizes, int n_in,
                              void* d_out, int out_size, void* d_ws, size_t ws_size,
                              hipStream_t stream) {
    const float* uw   = (const float*)d_in[0];
    const float* iw   = (const float*)d_in[1];
    const float* vals = (const float*)d_in[2];
    const int*   rows = (const int*)d_in[3];
    const int*   cols = (const int*)d_in[4];
    const int*   ui   = (const int*)d_in[5];
    const int*   ii   = (const int*)d_in[6];
    float* out = (float*)d_out;

    const int n_users = in_sizes[0] / D;
    const int n_items = in_sizes[1] / D;
    const int n_nodes = n_users + n_items;
    const int n_edges = in_sizes[2];
    const int nq      = in_sizes[5];

    const size_t buf_elems = (size_t)n_nodes * D;
    const int nb = (n_nodes + RB - 1) / RB;          // row buckets

    // ---- workspace carve ----
    size_t off = 0;
    float* bufA    = (float*)((char*)d_ws + off); off += buf_elems * 4;
    float* bufB    = (float*)((char*)d_ws + off); off += buf_elems * 4;
    int*   cnt     = (int*)  ((char*)d_ws + off); off += (size_t)n_nodes * 4;
    int*   rstart  = (int*)  ((char*)d_ws + off); off += (size_t)n_nodes * 4;
    int*   fill    = (int*)  ((char*)d_ws + off); off += (size_t)n_nodes * 4;
    int*   bsum    = (int*)  ((char*)d_ws + off); off += 4096 * 4;
    int*   bktFill = (int*)  ((char*)d_ws + off); off += 4096 * 4;
    unsigned char* flag = (unsigned char*)((char*)d_ws + off);
    off += ((size_t)n_nodes + 255) & ~(size_t)255;
    int2*  cedge   = (int2*) ((char*)d_ws + off); off += (size_t)n_edges * 8;
    int2*  staging = (int2*) ((char*)d_ws + off); off += (size_t)n_edges * 8;

    const int nblk_scan = (n_nodes + 1023) / 1024;
    const int gq = (2 * nq * D + 255) / 256;
    const bool csr_ok = (off <= ws_size) && (nblk_scan <= 1024) &&
                        (nb <= NBMAX) && (n_nodes < (1 << COL_BITS));

    if (csr_ok) {
        // ---- CSR build ----
        hipMemsetAsync(cnt, 0, (size_t)n_nodes * 4, stream);
        hipMemsetAsync(flag, 0, (size_t)n_nodes, stream);
        k_count<<<(n_edges + 255) / 256, 256, 0, stream>>>(rows, cnt, n_edges);
        k_scan1<<<nblk_scan, 1024, 0, stream>>>(cnt, rstart, bsum, n_nodes);
        k_scan2<<<1, 1024, 0, stream>>>(bsum, nblk_scan);
        k_scan3<<<nblk_scan, 1024, 0, stream>>>(rstart, fill, bsum, bktFill, n_nodes);
        k_binpart<<<(n_edges + TILE - 1) / TILE, 256, 0, stream>>>(
            vals, rows, cols, bktFill, staging, n_edges, nb);
        k_place2<<<nb, 256, 0, stream>>>(rstart, staging, fill, cedge, n_nodes, n_edges);

        // mark nodes whose layer-2 output is actually consumed
        k_mark<<<(2 * nq + 255) / 256, 256, 0, stream>>>(
            rstart, cnt, cedge, ui, ii, n_users, flag, nq);

        // ---- layer 0 gather ----
        k_gather_init<<<gq, 256, 0, stream>>>(uw, iw, ui, ii, out, nq);

        const int gs = (n_nodes + 15) / 16;
        // ---- layer 1: emb -> bufA (all rows) ----
        k_spmm_csr<<<gs, 256, 0, stream>>>(rstart, cnt, cedge,
                                           uw, iw, n_users, bufA, n_nodes, nullptr);
        k_gather_acc<<<gq, 256, 0, stream>>>(bufA, ui, ii, n_users, out, nq, 1.0f);

        // ---- layer 2: bufA -> bufB (marked rows only) ----
        k_spmm_csr<<<gs, 256, 0, stream>>>(rstart, cnt, cedge,
                                           bufA, bufA + (size_t)n_users * D,
                                           n_users, bufB, n_nodes, flag);
        k_gather_acc<<<gq, 256, 0, stream>>>(bufB, ui, ii, n_users, out, nq, 1.0f);

        // ---- layer 3: per-query only ----
        k_final<<<(2 * nq + 15) / 16, 256, 0, stream>>>(
            rstart, cnt, cedge, bufB, ui, ii, n_users, out, nq, 0.25f);
    } else {
        // ---- fallback: atomic path ----
        hipMemsetAsync(bufA, 0, 2 * buf_elems * 4, stream);
        const int gs = 8192;
        k_gather_init<<<gq, 256, 0, stream>>>(uw, iw, ui, ii, out, nq);
        k_spmm_l0<<<gs, 256, 0, stream>>>(vals, rows, cols, uw, iw, n_users, bufA, n_edges);
        k_gather_acc<<<gq, 256, 0, stream>>>(bufA, ui, ii, n_users, out, nq, 1.0f);
        k_spmm<<<gs, 256, 0, stream>>>(vals, rows, cols, bufA, bufB, n_edges);
        k_gather_acc<<<gq, 256, 0, stream>>>(bufB, ui, ii, n_users, out, nq, 1.0f);
        hipMemsetAsync(bufA, 0, buf_elems * 4, stream);
        k_spmm<<<gs, 256, 0, stream>>>(vals, rows, cols, bufB, bufA, n_edges);
        k_gather_acc<<<gq, 256, 0, stream>>>(bufA, ui, ii, n_users, out, nq, 0.25f);
    }
}

// Round 9
// 420.341 us; speedup vs baseline: 1.2598x; 1.0645x over previous
//
#include <hip/hip_runtime.h>

#define D 64
#define RB 512            // rows per bucket (pow2)
#define RB_SHIFT 9
#define COL_BITS 19
#define COL_MASK ((1u << COL_BITS) - 1u)
#define CAP 4096          // max staged edges per bucket held in LDS
#define NBMAX 640         // max buckets supported by k_binpart LDS arrays
#define TILE 4096         // edges per k_binpart block (round-6 proven value)

// ---------------- bf16 helpers (storage bf16, math f32) --------------------
__device__ __forceinline__ float bf_lo(unsigned u) { return __uint_as_float(u << 16); }
__device__ __forceinline__ float bf_hi(unsigned u) { return __uint_as_float(u & 0xffff0000u); }
__device__ __forceinline__ unsigned pack_bf2(float a, float b) {
    unsigned ua = __float_as_uint(a), ub = __float_as_uint(b);
    ua += 0x7fffu + ((ua >> 16) & 1u);           // round-to-nearest-even
    ub += 0x7fffu + ((ub >> 16) & 1u);
    return (ua >> 16) | (ub & 0xffff0000u);
}

// ============================ small kernels =================================

// f32 -> bf16 pack: n2 = number of float PAIRS
__global__ __launch_bounds__(256) void k_tobf(
    const float* __restrict__ src, unsigned* __restrict__ dst, int n2)
{
    int stride = gridDim.x * 256;
    for (int i = blockIdx.x * 256 + threadIdx.x; i < n2; i += stride) {
        float2 v = ((const float2*)src)[i];
        dst[i] = pack_bf2(v.x, v.y);
    }
}

// layer-0: out rows straight from f32 embedding tables (full accuracy)
__global__ __launch_bounds__(256) void k_gather_init(
    const float* __restrict__ uw, const float* __restrict__ iw,
    const int* __restrict__ ui, const int* __restrict__ ii,
    float* __restrict__ out, int nq)
{
    int t = blockIdx.x * 256 + threadIdx.x;
    int total = nq * D;
    if (t < total) {
        int q = t >> 6, d = t & 63;
        out[t] = uw[ui[q] * D + d];
    } else if (t < 2 * total) {
        int u = t - total;
        int q = u >> 6, d = u & 63;
        out[t] = iw[ii[q] * D + d];
    }
}

// out[q] = (out[q] + bf16src[node]) * scale   (16 lanes/row, 4 f32 per lane)
__global__ __launch_bounds__(256) void k_gather_acc_bf(
    const uint2* __restrict__ src,
    const int* __restrict__ ui, const int* __restrict__ ii,
    int n_users, float* __restrict__ out, int nq, float scale)
{
    int lane16 = threadIdx.x & 15;
    int q = blockIdx.x * 16 + (threadIdx.x >> 4);
    if (q >= 2 * nq) return;
    int node = (q < nq) ? ui[q] : n_users + ii[q - nq];
    uint2 x = src[(size_t)node * 16 + lane16];
    float4* o = (float4*)&out[(size_t)q * D + lane16 * 4];
    float4 v = *o;
    v.x = (v.x + bf_lo(x.x)) * scale;
    v.y = (v.y + bf_hi(x.x)) * scale;
    v.z = (v.z + bf_lo(x.y)) * scale;
    v.w = (v.w + bf_hi(x.y)) * scale;
    *o = v;
}

// ============================== CSR build ===================================

__global__ __launch_bounds__(256) void k_count(
    const int* __restrict__ rows, int* __restrict__ cnt, int ne)
{
    int e = blockIdx.x * 256 + threadIdx.x;
    if (e < ne) atomicAdd(&cnt[rows[e]], 1);
}

__global__ __launch_bounds__(1024) void k_scan1(
    const int* __restrict__ cnt, int* __restrict__ rstart,
    int* __restrict__ bsum, int n)
{
    __shared__ int s[1024];
    int t = threadIdx.x, i = blockIdx.x * 1024 + t;
    int v = (i < n) ? cnt[i] : 0;
    s[t] = v; __syncthreads();
    for (int off = 1; off < 1024; off <<= 1) {
        int x = (t >= off) ? s[t - off] : 0;
        __syncthreads();
        s[t] += x;
        __syncthreads();
    }
    if (i < n) rstart[i] = s[t] - v;
    if (t == 1023) bsum[blockIdx.x] = s[t];
}

__global__ __launch_bounds__(1024) void k_scan2(int* __restrict__ bsum, int nb)
{
    __shared__ int s[1024];
    int t = threadIdx.x;
    int v = (t < nb) ? bsum[t] : 0;
    s[t] = v; __syncthreads();
    for (int off = 1; off < 1024; off <<= 1) {
        int x = (t >= off) ? s[t - off] : 0;
        __syncthreads();
        s[t] += x;
        __syncthreads();
    }
    if (t < nb) bsum[t] = s[t] - v;
}

__global__ __launch_bounds__(1024) void k_scan3(
    int* __restrict__ rstart, int* __restrict__ fill,
    const int* __restrict__ bsum, int* __restrict__ bucketFill, int n)
{
    int i = blockIdx.x * 1024 + threadIdx.x;
    if (i < n) {
        int v = rstart[i] + bsum[blockIdx.x];
        rstart[i] = v;
        fill[i] = v;
        if ((i & (RB - 1)) == 0) bucketFill[i >> RB_SHIFT] = v;
    }
}

// ---- stage B: partition edges into row-buckets (ROUND-6 PROVEN VERSION) ----
// staging[p] = { (localrow<<COL_BITS)|col , val }
__global__ __launch_bounds__(256) void k_binpart(
    const float* __restrict__ vals, const int* __restrict__ rows,
    const int* __restrict__ cols,
    int* __restrict__ bucketFill, int2* __restrict__ staging,
    int ne, int nb)
{
    __shared__ int shist[NBMAX];
    __shared__ int sgb[NBMAX];
    int tid = threadIdx.x;
    int base = blockIdx.x * TILE;

    for (int b = tid; b < nb; b += 256) shist[b] = 0;
    __syncthreads();

    int myb[TILE / 256];
    int myr[TILE / 256];
    for (int k = 0; k < TILE / 256; ++k) {
        int e = base + k * 256 + tid;
        int b = -1, r = 0;
        if (e < ne) {
            r = rows[e];
            b = r >> RB_SHIFT;
            atomicAdd(&shist[b], 1);
        }
        myb[k] = b; myr[k] = r;
    }
    __syncthreads();
    for (int b = tid; b < nb; b += 256) {
        int c = shist[b];
        sgb[b] = (c > 0) ? atomicAdd(&bucketFill[b], c) : 0;
        shist[b] = 0;
    }
    __syncthreads();
    for (int k = 0; k < TILE / 256; ++k) {
        int e = base + k * 256 + tid;
        if (e >= ne) continue;
        int b = myb[k];
        int lofs = atomicAdd(&shist[b], 1);
        int2 pk;
        pk.x = (int)((((unsigned)myr[k] & (RB - 1)) << COL_BITS) | (unsigned)cols[e]);
        pk.y = __float_as_int(vals[e]);
        staging[sgb[b] + lofs] = pk;
    }
}

// ---- stage C: within-bucket ordering in LDS, coalesced stream-out ----------
__global__ __launch_bounds__(256) void k_place2(
    const int* __restrict__ rstart, const int2* __restrict__ staging,
    int* __restrict__ fill, int2* __restrict__ cedge, int n_nodes, int ne)
{
    __shared__ int cursor[RB];
    __shared__ int2 ebuf[CAP];
    int b = blockIdx.x;
    int rowbase = b << RB_SHIFT;
    int s = rstart[rowbase];
    int nextrow = rowbase + RB;
    int e = (nextrow < n_nodes) ? rstart[nextrow] : ne;
    int cnt = e - s;

    if (cnt <= CAP) {
        for (int i = threadIdx.x; i < RB; i += 256) {
            int r = rowbase + i;
            cursor[i] = ((r < n_nodes) ? rstart[r] : ne) - s;
        }
        __syncthreads();
        for (int p = s + threadIdx.x; p < e; p += 256) {
            int2 pk = staging[p];
            int lr = ((unsigned)pk.x) >> COL_BITS;
            int pos = atomicAdd(&cursor[lr], 1);
            pk.x = (int)((unsigned)pk.x & COL_MASK);
            ebuf[pos] = pk;
        }
        __syncthreads();
        for (int p = threadIdx.x; p < cnt; p += 256)
            cedge[s + p] = ebuf[p];
    } else {
        for (int p = s + threadIdx.x; p < e; p += 256) {
            int2 pk = staging[p];
            int lr = ((unsigned)pk.x) >> COL_BITS;
            int r = rowbase + lr;
            int pos = atomicAdd(&fill[r], 1);
            pk.x = (int)((unsigned)pk.x & COL_MASK);
            cedge[pos] = pk;
        }
    }
}

// mark nodes whose layer-2 value is needed: Q itself and neighbors(Q)
__global__ __launch_bounds__(256) void k_mark(
    const int* __restrict__ rstart, const int* __restrict__ cnt,
    const int2* __restrict__ cedge,
    const int* __restrict__ ui, const int* __restrict__ ii,
    int n_users, unsigned char* __restrict__ flag, int nq)
{
    int q = blockIdx.x * 256 + threadIdx.x;
    if (q >= 2 * nq) return;
    int node = (q < nq) ? ui[q] : n_users + ii[q - nq];
    flag[node] = 1;
    int s = rstart[node], dg = cnt[node];
    for (int j = 0; j < dg; ++j) flag[cedge[s + j].x] = 1;
}

// ========================= CSR SpMM (bf16 src/dst) ==========================
// 16 lanes per row; each lane owns 4 consecutive dims (one uint2 = 4 bf16).
__global__ __launch_bounds__(256) void k_spmm_bf(
    const int* __restrict__ rstart, const int* __restrict__ cnt,
    const int2* __restrict__ cedge,
    const uint2* __restrict__ src,        // concat node table, 16 uint2/node
    uint2* __restrict__ dst, int n_nodes,
    const unsigned char* __restrict__ flag)
{
    int lane16 = threadIdx.x & 15;
    int row = blockIdx.x * 16 + (threadIdx.x >> 4);
    if (row >= n_nodes) return;
    if (flag && !flag[row]) return;

    int s = rstart[row], dg = cnt[row];
    float a0 = 0, a1 = 0, a2 = 0, a3 = 0;
    int j = 0;
    for (; j + 3 < dg; j += 4) {
        int2 e0 = cedge[s + j],     e1 = cedge[s + j + 1];
        int2 e2 = cedge[s + j + 2], e3 = cedge[s + j + 3];
        uint2 x0 = src[(size_t)e0.x * 16 + lane16];
        uint2 x1 = src[(size_t)e1.x * 16 + lane16];
        uint2 x2 = src[(size_t)e2.x * 16 + lane16];
        uint2 x3 = src[(size_t)e3.x * 16 + lane16];
        float v0 = __int_as_float(e0.y), v1 = __int_as_float(e1.y);
        float v2 = __int_as_float(e2.y), v3 = __int_as_float(e3.y);
        a0 += v0 * bf_lo(x0.x); a1 += v0 * bf_hi(x0.x); a2 += v0 * bf_lo(x0.y); a3 += v0 * bf_hi(x0.y);
        a0 += v1 * bf_lo(x1.x); a1 += v1 * bf_hi(x1.x); a2 += v1 * bf_lo(x1.y); a3 += v1 * bf_hi(x1.y);
        a0 += v2 * bf_lo(x2.x); a1 += v2 * bf_hi(x2.x); a2 += v2 * bf_lo(x2.y); a3 += v2 * bf_hi(x2.y);
        a0 += v3 * bf_lo(x3.x); a1 += v3 * bf_hi(x3.x); a2 += v3 * bf_lo(x3.y); a3 += v3 * bf_hi(x3.y);
    }
    for (; j < dg; ++j) {
        int2 e0 = cedge[s + j];
        uint2 x0 = src[(size_t)e0.x * 16 + lane16];
        float v0 = __int_as_float(e0.y);
        a0 += v0 * bf_lo(x0.x); a1 += v0 * bf_hi(x0.x); a2 += v0 * bf_lo(x0.y); a3 += v0 * bf_hi(x0.y);
    }
    uint2 o;
    o.x = pack_bf2(a0, a1);
    o.y = pack_bf2(a2, a3);
    dst[(size_t)row * 16 + lane16] = o;
}

// ======================= layer-3: per-query CSR walk ========================
__global__ __launch_bounds__(256) void k_final_bf(
    const int* __restrict__ rstart, const int* __restrict__ cnt,
    const int2* __restrict__ cedge,
    const uint2* __restrict__ src,
    const int* __restrict__ ui, const int* __restrict__ ii,
    int n_users, float* __restrict__ out, int nq, float scale)
{
    int lane16 = threadIdx.x & 15;
    int q = blockIdx.x * 16 + (threadIdx.x >> 4);
    if (q >= 2 * nq) return;
    int node = (q < nq) ? ui[q] : n_users + ii[q - nq];

    int s = rstart[node], dg = cnt[node];
    float4* op = (float4*)&out[(size_t)q * D + lane16 * 4];
    float4 a = *op;
    int j = 0;
    for (; j + 1 < dg; j += 2) {
        int2 e0 = cedge[s + j], e1 = cedge[s + j + 1];
        uint2 x0 = src[(size_t)e0.x * 16 + lane16];
        uint2 x1 = src[(size_t)e1.x * 16 + lane16];
        float v0 = __int_as_float(e0.y), v1 = __int_as_float(e1.y);
        a.x += v0 * bf_lo(x0.x) + v1 * bf_lo(x1.x);
        a.y += v0 * bf_hi(x0.x) + v1 * bf_hi(x1.x);
        a.z += v0 * bf_lo(x0.y) + v1 * bf_lo(x1.y);
        a.w += v0 * bf_hi(x0.y) + v1 * bf_hi(x1.y);
    }
    if (j < dg) {
        int2 e0 = cedge[s + j];
        uint2 x0 = src[(size_t)e0.x * 16 + lane16];
        float v0 = __int_as_float(e0.y);
        a.x += v0 * bf_lo(x0.x); a.y += v0 * bf_hi(x0.x);
        a.z += v0 * bf_lo(x0.y); a.w += v0 * bf_hi(x0.y);
    }
    a.x *= scale; a.y *= scale; a.z *= scale; a.w *= scale;
    *op = a;
}

// ===================== fallback (atomic path, f32) ==========================

__global__ __launch_bounds__(256) void k_gather_acc(
    const float* __restrict__ src,
    const int* __restrict__ ui, const int* __restrict__ ii,
    int n_users, float* __restrict__ out, int nq, float scale)
{
    int t = blockIdx.x * 256 + threadIdx.x;
    int total = nq * D;
    if (t < total) {
        int q = t >> 6, d = t & 63;
        out[t] = (out[t] + src[ui[q] * D + d]) * scale;
    } else if (t < 2 * total) {
        int u = t - total;
        int q = u >> 6, d = u & 63;
        out[t] = (out[t] + src[(n_users + ii[q]) * D + d]) * scale;
    }
}

__global__ __launch_bounds__(256) void k_spmm_l0(
    const float* __restrict__ vals, const int* __restrict__ rows,
    const int* __restrict__ cols,
    const float* __restrict__ uw, const float* __restrict__ iw, int n_users,
    float* __restrict__ dst, int n_edges)
{
    int total = n_edges * D;
    int stride = gridDim.x * 256;
    for (int t = blockIdx.x * 256 + threadIdx.x; t < total; t += stride) {
        int e = t >> 6, d = t & 63;
        float v = vals[e];
        int c = cols[e], r = rows[e];
        float x = (c < n_users) ? uw[c * D + d] : iw[(c - n_users) * D + d];
        atomicAdd(dst + r * D + d, v * x);
    }
}

__global__ __launch_bounds__(256) void k_spmm(
    const float* __restrict__ vals, const int* __restrict__ rows,
    const int* __restrict__ cols,
    const float* __restrict__ src, float* __restrict__ dst, int n_edges)
{
    int total = n_edges * D;
    int stride = gridDim.x * 256;
    for (int t = blockIdx.x * 256 + threadIdx.x; t < total; t += stride) {
        int e = t >> 6, d = t & 63;
        float v = vals[e];
        int c = cols[e], r = rows[e];
        atomicAdd(dst + r * D + d, v * src[c * D + d]);
    }
}

// ============================================================================

extern "C" void kernel_launch(void* const* d_in, const int* in_sizes, int n_in,
                              void* d_out, int out_size, void* d_ws, size_t ws_size,
                              hipStream_t stream) {
    const float* uw   = (const float*)d_in[0];
    const float* iw   = (const float*)d_in[1];
    const float* vals = (const float*)d_in[2];
    const int*   rows = (const int*)d_in[3];
    const int*   cols = (const int*)d_in[4];
    const int*   ui   = (const int*)d_in[5];
    const int*   ii   = (const int*)d_in[6];
    float* out = (float*)d_out;

    const int n_users = in_sizes[0] / D;
    const int n_items = in_sizes[1] / D;
    const int n_nodes = n_users + n_items;
    const int n_edges = in_sizes[2];
    const int nq      = in_sizes[5];

    const int nb = (n_nodes + RB - 1) / RB;

    // ---- workspace carve (common small arrays, then path-specific big) ----
    size_t off = 0;
    int* cnt     = (int*)((char*)d_ws + off); off += (size_t)n_nodes * 4;
    int* rstart  = (int*)((char*)d_ws + off); off += (size_t)n_nodes * 4;
    int* fill    = (int*)((char*)d_ws + off); off += (size_t)n_nodes * 4;
    int* bsum    = (int*)((char*)d_ws + off); off += 4096 * 4;
    int* bktFill = (int*)((char*)d_ws + off); off += 4096 * 4;
    unsigned char* flag = (unsigned char*)((char*)d_ws + off);
    off += ((size_t)n_nodes + 255) & ~(size_t)255;
    size_t big = off;

    // csr path: bf16 tables + edge arrays
    size_t coff = big;
    unsigned* embB  = (unsigned*)((char*)d_ws + coff); coff += (size_t)n_nodes * D * 2;
    unsigned* bufAh = (unsigned*)((char*)d_ws + coff); coff += (size_t)n_nodes * D * 2;
    unsigned* bufBh = (unsigned*)((char*)d_ws + coff); coff += (size_t)n_nodes * D * 2;
    int2* cedge   = (int2*)((char*)d_ws + coff); coff += (size_t)n_edges * 8;
    int2* staging = (int2*)((char*)d_ws + coff); coff += (size_t)n_edges * 8;

    // fallback path: two f32 node buffers
    size_t foff = big;
    float* bufA = (float*)((char*)d_ws + foff); foff += (size_t)n_nodes * D * 4;
    float* bufB = (float*)((char*)d_ws + foff); foff += (size_t)n_nodes * D * 4;

    const int nblk_scan = (n_nodes + 1023) / 1024;
    const int gq = (2 * nq * D + 255) / 256;
    const bool csr_ok = (coff <= ws_size) && (nblk_scan <= 1024) &&
                        (nb <= NBMAX) && (n_nodes < (1 << COL_BITS));

    if (csr_ok) {
        // ---- bf16 conversion of embedding tables (streamed once) ----
        k_tobf<<<2048, 256, 0, stream>>>(uw, embB, n_users * (D / 2));
        k_tobf<<<2048, 256, 0, stream>>>(iw, embB + (size_t)n_users * (D / 2),
                                         n_items * (D / 2));

        // ---- CSR build (round-6 proven kernels) ----
        hipMemsetAsync(cnt, 0, (size_t)n_nodes * 4, stream);
        hipMemsetAsync(flag, 0, (size_t)n_nodes, stream);
        k_count<<<(n_edges + 255) / 256, 256, 0, stream>>>(rows, cnt, n_edges);
        k_scan1<<<nblk_scan, 1024, 0, stream>>>(cnt, rstart, bsum, n_nodes);
        k_scan2<<<1, 1024, 0, stream>>>(bsum, nblk_scan);
        k_scan3<<<nblk_scan, 1024, 0, stream>>>(rstart, fill, bsum, bktFill, n_nodes);
        k_binpart<<<(n_edges + TILE - 1) / TILE, 256, 0, stream>>>(
            vals, rows, cols, bktFill, staging, n_edges, nb);
        k_place2<<<nb, 256, 0, stream>>>(rstart, staging, fill, cedge, n_nodes, n_edges);
        k_mark<<<(2 * nq + 255) / 256, 256, 0, stream>>>(
            rstart, cnt, cedge, ui, ii, n_users, flag, nq);

        // ---- layer 0 gather (f32 tables, full accuracy) ----
        k_gather_init<<<gq, 256, 0, stream>>>(uw, iw, ui, ii, out, nq);

        const int gs = (n_nodes + 15) / 16;
        const int gq16 = (2 * nq + 15) / 16;
        // ---- layer 1: embB -> bufAh (all rows) ----
        k_spmm_bf<<<gs, 256, 0, stream>>>(rstart, cnt, cedge, (const uint2*)embB,
                                          (uint2*)bufAh, n_nodes, nullptr);
        k_gather_acc_bf<<<gq16, 256, 0, stream>>>((const uint2*)bufAh, ui, ii,
                                                  n_users, out, nq, 1.0f);
        // ---- layer 2: bufAh -> bufBh (marked rows only) ----
        k_spmm_bf<<<gs, 256, 0, stream>>>(rstart, cnt, cedge, (const uint2*)bufAh,
                                          (uint2*)bufBh, n_nodes, flag);
        k_gather_acc_bf<<<gq16, 256, 0, stream>>>((const uint2*)bufBh, ui, ii,
                                                  n_users, out, nq, 1.0f);
        // ---- layer 3: per-query only ----
        k_final_bf<<<gq16, 256, 0, stream>>>(rstart, cnt, cedge, (const uint2*)bufBh,
                                             ui, ii, n_users, out, nq, 0.25f);
    } else {
        // ---- fallback: atomic f32 path ----
        hipMemsetAsync(bufA, 0, 2 * (size_t)n_nodes * D * 4, stream);
        const int gs = 8192;
        k_gather_init<<<gq, 256, 0, stream>>>(uw, iw, ui, ii, out, nq);
        k_spmm_l0<<<gs, 256, 0, stream>>>(vals, rows, cols, uw, iw, n_users, bufA, n_edges);
        k_gather_acc<<<gq, 256, 0, stream>>>(bufA, ui, ii, n_users, out, nq, 1.0f);
        k_spmm<<<gs, 256, 0, stream>>>(vals, rows, cols, bufA, bufB, n_edges);
        k_gather_acc<<<gq, 256, 0, stream>>>(bufB, ui, ii, n_users, out, nq, 1.0f);
        hipMemsetAsync(bufA, 0, (size_t)n_nodes * D * 4, stream);
        k_spmm<<<gs, 256, 0, stream>>>(vals, rows, cols, bufB, bufA, n_edges);
        k_gather_acc<<<gq, 256, 0, stream>>>(bufA, ui, ii, n_users, out, nq, 0.25f);
    }
}

// Round 10
// 354.616 us; speedup vs baseline: 1.4933x; 1.1853x over previous
//
#include <hip/hip_runtime.h>

#define D 64
#define RB 512            // rows per bucket (pow2)
#define RB_SHIFT 9
#define COL_BITS 19
#define COL_MASK ((1u << COL_BITS) - 1u)
#define CAP 4096          // max staged edges per bucket held in LDS
#define NBMAX 640         // max buckets supported by LDS arrays
#define TILE 4096         // edges per k_binpart/k_bcount block

// ---------------- bf16 helpers (storage bf16, math f32) --------------------
__device__ __forceinline__ float bf_lo(unsigned u) { return __uint_as_float(u << 16); }
__device__ __forceinline__ float bf_hi(unsigned u) { return __uint_as_float(u & 0xffff0000u); }
__device__ __forceinline__ unsigned pack_bf2(float a, float b) {
    unsigned ua = __float_as_uint(a), ub = __float_as_uint(b);
    ua += 0x7fffu + ((ua >> 16) & 1u);           // round-to-nearest-even
    ub += 0x7fffu + ((ub >> 16) & 1u);
    return (ua >> 16) | (ub & 0xffff0000u);
}

// ============================ small kernels =================================

// f32 -> bf16 pack: n2 = number of float PAIRS
__global__ __launch_bounds__(256) void k_tobf(
    const float* __restrict__ src, unsigned* __restrict__ dst, int n2)
{
    int stride = gridDim.x * 256;
    for (int i = blockIdx.x * 256 + threadIdx.x; i < n2; i += stride) {
        float2 v = ((const float2*)src)[i];
        dst[i] = pack_bf2(v.x, v.y);
    }
}

// layer-0: out rows straight from f32 embedding tables (full accuracy)
__global__ __launch_bounds__(256) void k_gather_init(
    const float* __restrict__ uw, const float* __restrict__ iw,
    const int* __restrict__ ui, const int* __restrict__ ii,
    float* __restrict__ out, int nq)
{
    int t = blockIdx.x * 256 + threadIdx.x;
    int total = nq * D;
    if (t < total) {
        int q = t >> 6, d = t & 63;
        out[t] = uw[ui[q] * D + d];
    } else if (t < 2 * total) {
        int u = t - total;
        int q = u >> 6, d = u & 63;
        out[t] = iw[ii[q] * D + d];
    }
}

// out[q] = (out[q] + bf16src[node]) * scale   (16 lanes/row, 4 f32 per lane)
__global__ __launch_bounds__(256) void k_gather_acc_bf(
    const uint2* __restrict__ src,
    const int* __restrict__ ui, const int* __restrict__ ii,
    int n_users, float* __restrict__ out, int nq, float scale)
{
    int lane16 = threadIdx.x & 15;
    int q = blockIdx.x * 16 + (threadIdx.x >> 4);
    if (q >= 2 * nq) return;
    int node = (q < nq) ? ui[q] : n_users + ii[q - nq];
    uint2 x = src[(size_t)node * 16 + lane16];
    float4* o = (float4*)&out[(size_t)q * D + lane16 * 4];
    float4 v = *o;
    v.x = (v.x + bf_lo(x.x)) * scale;
    v.y = (v.y + bf_hi(x.x)) * scale;
    v.z = (v.z + bf_lo(x.y)) * scale;
    v.w = (v.w + bf_hi(x.y)) * scale;
    *o = v;
}

// ============================== CSR build ===================================

// per-BUCKET histogram: LDS accumulation, one global atomic per block/bucket
__global__ __launch_bounds__(256) void k_bcount(
    const int* __restrict__ rows, int* __restrict__ bcnt, int ne, int nb)
{
    __shared__ int sh[NBMAX];
    int tid = threadIdx.x;
    int base = blockIdx.x * TILE;
    int end = base + TILE; if (end > ne) end = ne;
    for (int b = tid; b < nb; b += 256) sh[b] = 0;
    __syncthreads();
    for (int e = base + tid; e < end; e += 256)
        atomicAdd(&sh[rows[e] >> RB_SHIFT], 1);
    __syncthreads();
    for (int b = tid; b < nb; b += 256)
        if (sh[b]) atomicAdd(&bcnt[b], sh[b]);
}

// one-block exclusive scan of bucket counts -> bstart[0..nb] and binpart cursors
__global__ __launch_bounds__(1024) void k_bscan(
    const int* __restrict__ bcnt, int* __restrict__ bstart,
    int* __restrict__ bktFill, int nb)
{
    __shared__ int s[1024];
    int t = threadIdx.x;
    int v = (t < nb) ? bcnt[t] : 0;
    s[t] = v; __syncthreads();
    for (int off = 1; off < 1024; off <<= 1) {
        int x = (t >= off) ? s[t - off] : 0;
        __syncthreads();
        s[t] += x;
        __syncthreads();
    }
    int excl = s[t] - v;
    if (t <= nb) {
        bstart[t] = excl;            // t==nb -> total edge count
        if (t < nb) bktFill[t] = excl;
    }
}

// ---- stage B: partition edges into row-buckets (ROUND-6 PROVEN BODY) -------
// staging[p] = { (localrow<<COL_BITS)|col , val }
__global__ __launch_bounds__(256) void k_binpart(
    const float* __restrict__ vals, const int* __restrict__ rows,
    const int* __restrict__ cols,
    int* __restrict__ bucketFill, int2* __restrict__ staging,
    int ne, int nb)
{
    __shared__ int shist[NBMAX];
    __shared__ int sgb[NBMAX];
    int tid = threadIdx.x;
    int base = blockIdx.x * TILE;

    for (int b = tid; b < nb; b += 256) shist[b] = 0;
    __syncthreads();

    int myb[TILE / 256];
    int myr[TILE / 256];
    for (int k = 0; k < TILE / 256; ++k) {
        int e = base + k * 256 + tid;
        int b = -1, r = 0;
        if (e < ne) {
            r = rows[e];
            b = r >> RB_SHIFT;
            atomicAdd(&shist[b], 1);
        }
        myb[k] = b; myr[k] = r;
    }
    __syncthreads();
    for (int b = tid; b < nb; b += 256) {
        int c = shist[b];
        sgb[b] = (c > 0) ? atomicAdd(&bucketFill[b], c) : 0;
        shist[b] = 0;
    }
    __syncthreads();
    for (int k = 0; k < TILE / 256; ++k) {
        int e = base + k * 256 + tid;
        if (e >= ne) continue;
        int b = myb[k];
        int lofs = atomicAdd(&shist[b], 1);
        int2 pk;
        pk.x = (int)((((unsigned)myr[k] & (RB - 1)) << COL_BITS) | (unsigned)cols[e]);
        pk.y = __float_as_int(vals[e]);
        staging[sgb[b] + lofs] = pk;
    }
}

// ---- stage C: fused row-count + row-scan + ordered placement per bucket ----
__global__ __launch_bounds__(256) void k_place3(
    const int* __restrict__ bstart, const int2* __restrict__ staging,
    int* __restrict__ rstart, int* __restrict__ cnt,
    int2* __restrict__ cedge, int n_nodes, int ne)
{
    __shared__ int hist[RB];      // row counts, then scatter cursors
    __shared__ int excl[RB];      // exclusive row starts (bucket-local)
    __shared__ int ss[256];
    __shared__ int2 ebuf[CAP];
    int tid = threadIdx.x;
    int b = blockIdx.x;
    int rowbase = b << RB_SHIFT;
    int s = bstart[b], e = bstart[b + 1];
    int m = e - s;

    for (int i = tid; i < RB; i += 256) hist[i] = 0;
    __syncthreads();
    // pass 1: count local rows from staged edges
    for (int p = s + tid; p < e; p += 256)
        atomicAdd(&hist[((unsigned)staging[p].x) >> COL_BITS], 1);
    __syncthreads();

    // exclusive scan of hist[0..RB): 2 elems/thread + 256-wide scan
    int c0 = hist[2 * tid], c1 = hist[2 * tid + 1];
    int sum = c0 + c1;
    ss[tid] = sum; __syncthreads();
    for (int off = 1; off < 256; off <<= 1) {
        int x = (tid >= off) ? ss[tid - off] : 0;
        __syncthreads();
        ss[tid] += x;
        __syncthreads();
    }
    int ex = ss[tid] - sum;
    excl[2 * tid] = ex;
    excl[2 * tid + 1] = ex + c0;
    __syncthreads();

    // write global CSR row pointers/degrees for this bucket (coalesced)
    for (int i = tid; i < RB; i += 256) {
        int r = rowbase + i;
        if (r < n_nodes) { rstart[r] = s + excl[i]; cnt[r] = hist[i]; }
    }
    __syncthreads();
    // hist becomes the scatter cursor (= exclusive start)
    for (int i = tid; i < RB; i += 256) hist[i] = excl[i];
    __syncthreads();

    if (m <= CAP) {
        // pass 2: scatter into LDS at ordered positions, then stream out
        for (int p = s + tid; p < e; p += 256) {
            int2 pk = staging[p];
            int lr = ((unsigned)pk.x) >> COL_BITS;
            int pos = atomicAdd(&hist[lr], 1);
            pk.x = (int)((unsigned)pk.x & COL_MASK);
            ebuf[pos] = pk;
        }
        __syncthreads();
        for (int p = tid; p < m; p += 256)
            cedge[s + p] = ebuf[p];
    } else {
        // overflow fallback (statistically unreachable): direct global placement
        for (int p = s + tid; p < e; p += 256) {
            int2 pk = staging[p];
            int lr = ((unsigned)pk.x) >> COL_BITS;
            int pos = atomicAdd(&hist[lr], 1);
            pk.x = (int)((unsigned)pk.x & COL_MASK);
            cedge[s + pos] = pk;
        }
    }
}

// mark nodes whose layer-2 value is needed: Q itself and neighbors(Q)
__global__ __launch_bounds__(256) void k_mark(
    const int* __restrict__ rstart, const int* __restrict__ cnt,
    const int2* __restrict__ cedge,
    const int* __restrict__ ui, const int* __restrict__ ii,
    int n_users, unsigned char* __restrict__ flag, int nq)
{
    int q = blockIdx.x * 256 + threadIdx.x;
    if (q >= 2 * nq) return;
    int node = (q < nq) ? ui[q] : n_users + ii[q - nq];
    flag[node] = 1;
    int s = rstart[node], dg = cnt[node];
    for (int j = 0; j < dg; ++j) flag[cedge[s + j].x] = 1;
}

// ========================= CSR SpMM (bf16 src/dst) ==========================
__global__ __launch_bounds__(256) void k_spmm_bf(
    const int* __restrict__ rstart, const int* __restrict__ cnt,
    const int2* __restrict__ cedge,
    const uint2* __restrict__ src,        // concat node table, 16 uint2/node
    uint2* __restrict__ dst, int n_nodes,
    const unsigned char* __restrict__ flag)
{
    int lane16 = threadIdx.x & 15;
    int row = blockIdx.x * 16 + (threadIdx.x >> 4);
    if (row >= n_nodes) return;
    if (flag && !flag[row]) return;

    int s = rstart[row], dg = cnt[row];
    float a0 = 0, a1 = 0, a2 = 0, a3 = 0;
    int j = 0;
    for (; j + 3 < dg; j += 4) {
        int2 e0 = cedge[s + j],     e1 = cedge[s + j + 1];
        int2 e2 = cedge[s + j + 2], e3 = cedge[s + j + 3];
        uint2 x0 = src[(size_t)e0.x * 16 + lane16];
        uint2 x1 = src[(size_t)e1.x * 16 + lane16];
        uint2 x2 = src[(size_t)e2.x * 16 + lane16];
        uint2 x3 = src[(size_t)e3.x * 16 + lane16];
        float v0 = __int_as_float(e0.y), v1 = __int_as_float(e1.y);
        float v2 = __int_as_float(e2.y), v3 = __int_as_float(e3.y);
        a0 += v0 * bf_lo(x0.x); a1 += v0 * bf_hi(x0.x); a2 += v0 * bf_lo(x0.y); a3 += v0 * bf_hi(x0.y);
        a0 += v1 * bf_lo(x1.x); a1 += v1 * bf_hi(x1.x); a2 += v1 * bf_lo(x1.y); a3 += v1 * bf_hi(x1.y);
        a0 += v2 * bf_lo(x2.x); a1 += v2 * bf_hi(x2.x); a2 += v2 * bf_lo(x2.y); a3 += v2 * bf_hi(x2.y);
        a0 += v3 * bf_lo(x3.x); a1 += v3 * bf_hi(x3.x); a2 += v3 * bf_lo(x3.y); a3 += v3 * bf_hi(x3.y);
    }
    for (; j < dg; ++j) {
        int2 e0 = cedge[s + j];
        uint2 x0 = src[(size_t)e0.x * 16 + lane16];
        float v0 = __int_as_float(e0.y);
        a0 += v0 * bf_lo(x0.x); a1 += v0 * bf_hi(x0.x); a2 += v0 * bf_lo(x0.y); a3 += v0 * bf_hi(x0.y);
    }
    uint2 o;
    o.x = pack_bf2(a0, a1);
    o.y = pack_bf2(a2, a3);
    dst[(size_t)row * 16 + lane16] = o;
}

// ======================= layer-3: per-query CSR walk ========================
__global__ __launch_bounds__(256) void k_final_bf(
    const int* __restrict__ rstart, const int* __restrict__ cnt,
    const int2* __restrict__ cedge,
    const uint2* __restrict__ src,
    const int* __restrict__ ui, const int* __restrict__ ii,
    int n_users, float* __restrict__ out, int nq, float scale)
{
    int lane16 = threadIdx.x & 15;
    int q = blockIdx.x * 16 + (threadIdx.x >> 4);
    if (q >= 2 * nq) return;
    int node = (q < nq) ? ui[q] : n_users + ii[q - nq];

    int s = rstart[node], dg = cnt[node];
    float4* op = (float4*)&out[(size_t)q * D + lane16 * 4];
    float4 a = *op;
    int j = 0;
    for (; j + 1 < dg; j += 2) {
        int2 e0 = cedge[s + j], e1 = cedge[s + j + 1];
        uint2 x0 = src[(size_t)e0.x * 16 + lane16];
        uint2 x1 = src[(size_t)e1.x * 16 + lane16];
        float v0 = __int_as_float(e0.y), v1 = __int_as_float(e1.y);
        a.x += v0 * bf_lo(x0.x) + v1 * bf_lo(x1.x);
        a.y += v0 * bf_hi(x0.x) + v1 * bf_hi(x1.x);
        a.z += v0 * bf_lo(x0.y) + v1 * bf_lo(x1.y);
        a.w += v0 * bf_hi(x0.y) + v1 * bf_hi(x1.y);
    }
    if (j < dg) {
        int2 e0 = cedge[s + j];
        uint2 x0 = src[(size_t)e0.x * 16 + lane16];
        float v0 = __int_as_float(e0.y);
        a.x += v0 * bf_lo(x0.x); a.y += v0 * bf_hi(x0.x);
        a.z += v0 * bf_lo(x0.y); a.w += v0 * bf_hi(x0.y);
    }
    a.x *= scale; a.y *= scale; a.z *= scale; a.w *= scale;
    *op = a;
}

// ===================== fallback (atomic path, f32) ==========================

__global__ __launch_bounds__(256) void k_gather_acc(
    const float* __restrict__ src,
    const int* __restrict__ ui, const int* __restrict__ ii,
    int n_users, float* __restrict__ out, int nq, float scale)
{
    int t = blockIdx.x * 256 + threadIdx.x;
    int total = nq * D;
    if (t < total) {
        int q = t >> 6, d = t & 63;
        out[t] = (out[t] + src[ui[q] * D + d]) * scale;
    } else if (t < 2 * total) {
        int u = t - total;
        int q = u >> 6, d = u & 63;
        out[t] = (out[t] + src[(n_users + ii[q]) * D + d]) * scale;
    }
}

__global__ __launch_bounds__(256) void k_spmm_l0(
    const float* __restrict__ vals, const int* __restrict__ rows,
    const int* __restrict__ cols,
    const float* __restrict__ uw, const float* __restrict__ iw, int n_users,
    float* __restrict__ dst, int n_edges)
{
    int total = n_edges * D;
    int stride = gridDim.x * 256;
    for (int t = blockIdx.x * 256 + threadIdx.x; t < total; t += stride) {
        int e = t >> 6, d = t & 63;
        float v = vals[e];
        int c = cols[e], r = rows[e];
        float x = (c < n_users) ? uw[c * D + d] : iw[(c - n_users) * D + d];
        atomicAdd(dst + r * D + d, v * x);
    }
}

__global__ __launch_bounds__(256) void k_spmm(
    const float* __restrict__ vals, const int* __restrict__ rows,
    const int* __restrict__ cols,
    const float* __restrict__ src, float* __restrict__ dst, int n_edges)
{
    int total = n_edges * D;
    int stride = gridDim.x * 256;
    for (int t = blockIdx.x * 256 + threadIdx.x; t < total; t += stride) {
        int e = t >> 6, d = t & 63;
        float v = vals[e];
        int c = cols[e], r = rows[e];
        atomicAdd(dst + r * D + d, v * src[c * D + d]);
    }
}

// ============================================================================

extern "C" void kernel_launch(void* const* d_in, const int* in_sizes, int n_in,
                              void* d_out, int out_size, void* d_ws, size_t ws_size,
                              hipStream_t stream) {
    const float* uw   = (const float*)d_in[0];
    const float* iw   = (const float*)d_in[1];
    const float* vals = (const float*)d_in[2];
    const int*   rows = (const int*)d_in[3];
    const int*   cols = (const int*)d_in[4];
    const int*   ui   = (const int*)d_in[5];
    const int*   ii   = (const int*)d_in[6];
    float* out = (float*)d_out;

    const int n_users = in_sizes[0] / D;
    const int n_items = in_sizes[1] / D;
    const int n_nodes = n_users + n_items;
    const int n_edges = in_sizes[2];
    const int nq      = in_sizes[5];

    const int nb = (n_nodes + RB - 1) / RB;

    // ---- workspace carve ----
    size_t off = 0;
    int* cnt     = (int*)((char*)d_ws + off); off += (size_t)n_nodes * 4;
    int* rstart  = (int*)((char*)d_ws + off); off += (size_t)n_nodes * 4;
    int* bstart  = (int*)((char*)d_ws + off); off += 4096 * 4;
    int* bcnt    = (int*)((char*)d_ws + off); off += 4096 * 4;
    int* bktFill = (int*)((char*)d_ws + off); off += 4096 * 4;
    unsigned char* flag = (unsigned char*)((char*)d_ws + off);
    off += ((size_t)n_nodes + 255) & ~(size_t)255;
    size_t big = off;

    // csr path: bf16 tables + edge arrays
    size_t coff = big;
    unsigned* embB  = (unsigned*)((char*)d_ws + coff); coff += (size_t)n_nodes * D * 2;
    unsigned* bufAh = (unsigned*)((char*)d_ws + coff); coff += (size_t)n_nodes * D * 2;
    unsigned* bufBh = (unsigned*)((char*)d_ws + coff); coff += (size_t)n_nodes * D * 2;
    int2* cedge   = (int2*)((char*)d_ws + coff); coff += (size_t)n_edges * 8;
    int2* staging = (int2*)((char*)d_ws + coff); coff += (size_t)n_edges * 8;

    // fallback path: two f32 node buffers
    size_t foff = big;
    float* bufA = (float*)((char*)d_ws + foff); foff += (size_t)n_nodes * D * 4;
    float* bufB = (float*)((char*)d_ws + foff); foff += (size_t)n_nodes * D * 4;

    const int gq = (2 * nq * D + 255) / 256;
    const bool csr_ok = (coff <= ws_size) && (nb < 1024) &&
                        (nb + 1 <= NBMAX) && (n_nodes < (1 << COL_BITS));

    if (csr_ok) {
        // ---- bf16 conversion of embedding tables (streamed once) ----
        k_tobf<<<2048, 256, 0, stream>>>(uw, embB, n_users * (D / 2));
        k_tobf<<<2048, 256, 0, stream>>>(iw, embB + (size_t)n_users * (D / 2),
                                         n_items * (D / 2));

        // ---- CSR build (bucket histogram -> scan -> partition -> fused place) ----
        hipMemsetAsync(bcnt, 0, 4096 * 4, stream);
        hipMemsetAsync(flag, 0, (size_t)n_nodes, stream);
        k_bcount<<<(n_edges + TILE - 1) / TILE, 256, 0, stream>>>(rows, bcnt, n_edges, nb);
        k_bscan<<<1, 1024, 0, stream>>>(bcnt, bstart, bktFill, nb);
        k_binpart<<<(n_edges + TILE - 1) / TILE, 256, 0, stream>>>(
            vals, rows, cols, bktFill, staging, n_edges, nb);
        k_place3<<<nb, 256, 0, stream>>>(bstart, staging, rstart, cnt,
                                         cedge, n_nodes, n_edges);
        k_mark<<<(2 * nq + 255) / 256, 256, 0, stream>>>(
            rstart, cnt, cedge, ui, ii, n_users, flag, nq);

        // ---- layer 0 gather (f32 tables, full accuracy) ----
        k_gather_init<<<gq, 256, 0, stream>>>(uw, iw, ui, ii, out, nq);

        const int gs = (n_nodes + 15) / 16;
        const int gq16 = (2 * nq + 15) / 16;
        // ---- layer 1: embB -> bufAh (all rows) ----
        k_spmm_bf<<<gs, 256, 0, stream>>>(rstart, cnt, cedge, (const uint2*)embB,
                                          (uint2*)bufAh, n_nodes, nullptr);
        k_gather_acc_bf<<<gq16, 256, 0, stream>>>((const uint2*)bufAh, ui, ii,
                                                  n_users, out, nq, 1.0f);
        // ---- layer 2: bufAh -> bufBh (marked rows only) ----
        k_spmm_bf<<<gs, 256, 0, stream>>>(rstart, cnt, cedge, (const uint2*)bufAh,
                                          (uint2*)bufBh, n_nodes, flag);
        k_gather_acc_bf<<<gq16, 256, 0, stream>>>((const uint2*)bufBh, ui, ii,
                                                  n_users, out, nq, 1.0f);
        // ---- layer 3: per-query only ----
        k_final_bf<<<gq16, 256, 0, stream>>>(rstart, cnt, cedge, (const uint2*)bufBh,
                                             ui, ii, n_users, out, nq, 0.25f);
    } else {
        // ---- fallback: atomic f32 path ----
        hipMemsetAsync(bufA, 0, 2 * (size_t)n_nodes * D * 4, stream);
        const int gs = 8192;
        k_gather_init<<<gq, 256, 0, stream>>>(uw, iw, ui, ii, out, nq);
        k_spmm_l0<<<gs, 256, 0, stream>>>(vals, rows, cols, uw, iw, n_users, bufA, n_edges);
        k_gather_acc<<<gq, 256, 0, stream>>>(bufA, ui, ii, n_users, out, nq, 1.0f);
        k_spmm<<<gs, 256, 0, stream>>>(vals, rows, cols, bufA, bufB, n_edges);
        k_gather_acc<<<gq, 256, 0, stream>>>(bufB, ui, ii, n_users, out, nq, 1.0f);
        hipMemsetAsync(bufA, 0, (size_t)n_nodes * D * 4, stream);
        k_spmm<<<gs, 256, 0, stream>>>(vals, rows, cols, bufB, bufA, n_edges);
        k_gather_acc<<<gq, 256, 0, stream>>>(bufA, ui, ii, n_users, out, nq, 0.25f);
    }
}

// Round 11
// 320.925 us; speedup vs baseline: 1.6500x; 1.1050x over previous
//
#include <hip/hip_runtime.h>

#define D 64
#define RB 512            // rows per bucket (pow2)
#define RB_SHIFT 9
#define COL_BITS 19
#define COL_MASK ((1u << COL_BITS) - 1u)
#define CAP 4096          // max staged edges per bucket held in LDS
#define NBMAX 640         // max buckets supported by LDS arrays
#define TILE 4096         // edges per k_binpart/k_bcount block

// ---------------- bf16 helpers (storage bf16, math f32) --------------------
__device__ __forceinline__ float bf_lo(unsigned u) { return __uint_as_float(u << 16); }
__device__ __forceinline__ float bf_hi(unsigned u) { return __uint_as_float(u & 0xffff0000u); }
__device__ __forceinline__ unsigned pack_bf2(float a, float b) {
    unsigned ua = __float_as_uint(a), ub = __float_as_uint(b);
    ua += 0x7fffu + ((ua >> 16) & 1u);           // round-to-nearest-even
    ub += 0x7fffu + ((ub >> 16) & 1u);
    return (ua >> 16) | (ub & 0xffff0000u);
}

// ============================ small kernels =================================

// f32 -> bf16 pack for BOTH tables: n2u/n2i = number of float PAIRS each
__global__ __launch_bounds__(256) void k_tobf2(
    const float* __restrict__ uw, const float* __restrict__ iw,
    unsigned* __restrict__ dst, int n2u, int n2i)
{
    int stride = gridDim.x * 256;
    int total = n2u + n2i;
    for (int i = blockIdx.x * 256 + threadIdx.x; i < total; i += stride) {
        float2 v = (i < n2u) ? ((const float2*)uw)[i]
                             : ((const float2*)iw)[i - n2u];
        dst[i] = pack_bf2(v.x, v.y);
    }
}

// ============================== CSR build ===================================

// per-BUCKET histogram: LDS accumulation, one global atomic per block/bucket
__global__ __launch_bounds__(256) void k_bcount(
    const int* __restrict__ rows, int* __restrict__ bcnt, int ne, int nb)
{
    __shared__ int sh[NBMAX];
    int tid = threadIdx.x;
    int base = blockIdx.x * TILE;
    int end = base + TILE; if (end > ne) end = ne;
    for (int b = tid; b < nb; b += 256) sh[b] = 0;
    __syncthreads();
    for (int e = base + tid; e < end; e += 256)
        atomicAdd(&sh[rows[e] >> RB_SHIFT], 1);
    __syncthreads();
    for (int b = tid; b < nb; b += 256)
        if (sh[b]) atomicAdd(&bcnt[b], sh[b]);
}

// one-block exclusive scan of bucket counts -> bstart[0..nb] and binpart cursors
__global__ __launch_bounds__(1024) void k_bscan(
    const int* __restrict__ bcnt, int* __restrict__ bstart,
    int* __restrict__ bktFill, int nb)
{
    __shared__ int s[1024];
    int t = threadIdx.x;
    int v = (t < nb) ? bcnt[t] : 0;
    s[t] = v; __syncthreads();
    for (int off = 1; off < 1024; off <<= 1) {
        int x = (t >= off) ? s[t - off] : 0;
        __syncthreads();
        s[t] += x;
        __syncthreads();
    }
    int excl = s[t] - v;
    if (t <= nb) {
        bstart[t] = excl;            // t==nb -> total edge count
        if (t < nb) bktFill[t] = excl;
    }
}

// ---- stage B: partition edges into row-buckets (ROUND-6 PROVEN BODY) -------
// staging[p] = { (localrow<<COL_BITS)|col , val }
__global__ __launch_bounds__(256) void k_binpart(
    const float* __restrict__ vals, const int* __restrict__ rows,
    const int* __restrict__ cols,
    int* __restrict__ bucketFill, int2* __restrict__ staging,
    int ne, int nb)
{
    __shared__ int shist[NBMAX];
    __shared__ int sgb[NBMAX];
    int tid = threadIdx.x;
    int base = blockIdx.x * TILE;

    for (int b = tid; b < nb; b += 256) shist[b] = 0;
    __syncthreads();

    int myb[TILE / 256];
    int myr[TILE / 256];
    for (int k = 0; k < TILE / 256; ++k) {
        int e = base + k * 256 + tid;
        int b = -1, r = 0;
        if (e < ne) {
            r = rows[e];
            b = r >> RB_SHIFT;
            atomicAdd(&shist[b], 1);
        }
        myb[k] = b; myr[k] = r;
    }
    __syncthreads();
    for (int b = tid; b < nb; b += 256) {
        int c = shist[b];
        sgb[b] = (c > 0) ? atomicAdd(&bucketFill[b], c) : 0;
        shist[b] = 0;
    }
    __syncthreads();
    for (int k = 0; k < TILE / 256; ++k) {
        int e = base + k * 256 + tid;
        if (e >= ne) continue;
        int b = myb[k];
        int lofs = atomicAdd(&shist[b], 1);
        int2 pk;
        pk.x = (int)((((unsigned)myr[k] & (RB - 1)) << COL_BITS) | (unsigned)cols[e]);
        pk.y = __float_as_int(vals[e]);
        staging[sgb[b] + lofs] = pk;
    }
}

// ---- stage C: fused row-count + row-scan + ordered placement per bucket ----
__global__ __launch_bounds__(256) void k_place3(
    const int* __restrict__ bstart, const int2* __restrict__ staging,
    int* __restrict__ rstart, int* __restrict__ cnt,
    int2* __restrict__ cedge, int n_nodes, int ne)
{
    __shared__ int hist[RB];      // row counts, then scatter cursors
    __shared__ int excl[RB];      // exclusive row starts (bucket-local)
    __shared__ int ss[256];
    __shared__ int2 ebuf[CAP];
    int tid = threadIdx.x;
    int b = blockIdx.x;
    int rowbase = b << RB_SHIFT;
    int s = bstart[b], e = bstart[b + 1];
    int m = e - s;

    for (int i = tid; i < RB; i += 256) hist[i] = 0;
    __syncthreads();
    // pass 1: count local rows from staged edges
    for (int p = s + tid; p < e; p += 256)
        atomicAdd(&hist[((unsigned)staging[p].x) >> COL_BITS], 1);
    __syncthreads();

    // exclusive scan of hist[0..RB): 2 elems/thread + 256-wide scan
    int c0 = hist[2 * tid], c1 = hist[2 * tid + 1];
    int sum = c0 + c1;
    ss[tid] = sum; __syncthreads();
    for (int off = 1; off < 256; off <<= 1) {
        int x = (tid >= off) ? ss[tid - off] : 0;
        __syncthreads();
        ss[tid] += x;
        __syncthreads();
    }
    int ex = ss[tid] - sum;
    excl[2 * tid] = ex;
    excl[2 * tid + 1] = ex + c0;
    __syncthreads();

    // write global CSR row pointers/degrees for this bucket (coalesced)
    for (int i = tid; i < RB; i += 256) {
        int r = rowbase + i;
        if (r < n_nodes) { rstart[r] = s + excl[i]; cnt[r] = hist[i]; }
    }
    __syncthreads();
    // hist becomes the scatter cursor (= exclusive start)
    for (int i = tid; i < RB; i += 256) hist[i] = excl[i];
    __syncthreads();

    if (m <= CAP) {
        for (int p = s + tid; p < e; p += 256) {
            int2 pk = staging[p];
            int lr = ((unsigned)pk.x) >> COL_BITS;
            int pos = atomicAdd(&hist[lr], 1);
            pk.x = (int)((unsigned)pk.x & COL_MASK);
            ebuf[pos] = pk;
        }
        __syncthreads();
        for (int p = tid; p < m; p += 256)
            cedge[s + p] = ebuf[p];
    } else {
        for (int p = s + tid; p < e; p += 256) {
            int2 pk = staging[p];
            int lr = ((unsigned)pk.x) >> COL_BITS;
            int pos = atomicAdd(&hist[lr], 1);
            pk.x = (int)((unsigned)pk.x & COL_MASK);
            cedge[s + pos] = pk;
        }
    }
}

// mark nodes whose layer-2 value is needed: Q itself and neighbors(Q)
__global__ __launch_bounds__(256) void k_mark(
    const int* __restrict__ rstart, const int* __restrict__ cnt,
    const int2* __restrict__ cedge,
    const int* __restrict__ ui, const int* __restrict__ ii,
    int n_users, unsigned char* __restrict__ flag, int nq)
{
    int q = blockIdx.x * 256 + threadIdx.x;
    if (q >= 2 * nq) return;
    int node = (q < nq) ? ui[q] : n_users + ii[q - nq];
    flag[node] = 1;
    int s = rstart[node], dg = cnt[node];
    for (int j = 0; j < dg; ++j) flag[cedge[s + j].x] = 1;
}

// ================= CSR SpMM (bf16 src/dst, 8 lanes/row, uint4) ==============
__global__ __launch_bounds__(256) void k_spmm_bf8(
    const int* __restrict__ rstart, const int* __restrict__ cnt,
    const int2* __restrict__ cedge,
    const uint4* __restrict__ src,        // concat node table, 8 uint4/node
    uint4* __restrict__ dst, int n_nodes,
    const unsigned char* __restrict__ flag)
{
    int lane8 = threadIdx.x & 7;
    int row = blockIdx.x * 32 + (threadIdx.x >> 3);
    if (row >= n_nodes) return;
    if (flag && !flag[row]) return;

    int s = rstart[row], dg = cnt[row];
    float a0 = 0, a1 = 0, a2 = 0, a3 = 0, a4 = 0, a5 = 0, a6 = 0, a7 = 0;
    int j = 0;
    for (; j + 3 < dg; j += 4) {
        int2 e0 = cedge[s + j],     e1 = cedge[s + j + 1];
        int2 e2 = cedge[s + j + 2], e3 = cedge[s + j + 3];
        uint4 x0 = src[(size_t)e0.x * 8 + lane8];
        uint4 x1 = src[(size_t)e1.x * 8 + lane8];
        uint4 x2 = src[(size_t)e2.x * 8 + lane8];
        uint4 x3 = src[(size_t)e3.x * 8 + lane8];
        float v0 = __int_as_float(e0.y), v1 = __int_as_float(e1.y);
        float v2 = __int_as_float(e2.y), v3 = __int_as_float(e3.y);
        a0 += v0 * bf_lo(x0.x); a1 += v0 * bf_hi(x0.x); a2 += v0 * bf_lo(x0.y); a3 += v0 * bf_hi(x0.y);
        a4 += v0 * bf_lo(x0.z); a5 += v0 * bf_hi(x0.z); a6 += v0 * bf_lo(x0.w); a7 += v0 * bf_hi(x0.w);
        a0 += v1 * bf_lo(x1.x); a1 += v1 * bf_hi(x1.x); a2 += v1 * bf_lo(x1.y); a3 += v1 * bf_hi(x1.y);
        a4 += v1 * bf_lo(x1.z); a5 += v1 * bf_hi(x1.z); a6 += v1 * bf_lo(x1.w); a7 += v1 * bf_hi(x1.w);
        a0 += v2 * bf_lo(x2.x); a1 += v2 * bf_hi(x2.x); a2 += v2 * bf_lo(x2.y); a3 += v2 * bf_hi(x2.y);
        a4 += v2 * bf_lo(x2.z); a5 += v2 * bf_hi(x2.z); a6 += v2 * bf_lo(x2.w); a7 += v2 * bf_hi(x2.w);
        a0 += v3 * bf_lo(x3.x); a1 += v3 * bf_hi(x3.x); a2 += v3 * bf_lo(x3.y); a3 += v3 * bf_hi(x3.y);
        a4 += v3 * bf_lo(x3.z); a5 += v3 * bf_hi(x3.z); a6 += v3 * bf_lo(x3.w); a7 += v3 * bf_hi(x3.w);
    }
    for (; j < dg; ++j) {
        int2 e0 = cedge[s + j];
        uint4 x0 = src[(size_t)e0.x * 8 + lane8];
        float v0 = __int_as_float(e0.y);
        a0 += v0 * bf_lo(x0.x); a1 += v0 * bf_hi(x0.x); a2 += v0 * bf_lo(x0.y); a3 += v0 * bf_hi(x0.y);
        a4 += v0 * bf_lo(x0.z); a5 += v0 * bf_hi(x0.z); a6 += v0 * bf_lo(x0.w); a7 += v0 * bf_hi(x0.w);
    }
    uint4 o;
    o.x = pack_bf2(a0, a1);
    o.y = pack_bf2(a2, a3);
    o.z = pack_bf2(a4, a5);
    o.w = pack_bf2(a6, a7);
    dst[(size_t)row * 8 + lane8] = o;
}

// ===== fused epilogue: out[q] = scale*(emb_f32 + bufA + bufB + Σ v·bufB[col]) =====
__global__ __launch_bounds__(256) void k_final_all(
    const int* __restrict__ rstart, const int* __restrict__ cnt,
    const int2* __restrict__ cedge,
    const float* __restrict__ uw, const float* __restrict__ iw,
    const uint4* __restrict__ bufA, const uint4* __restrict__ bufB,
    const int* __restrict__ ui, const int* __restrict__ ii,
    int n_users, float* __restrict__ out, int nq, float scale)
{
    int lane8 = threadIdx.x & 7;
    int q = blockIdx.x * 32 + (threadIdx.x >> 3);
    if (q >= 2 * nq) return;
    int node = (q < nq) ? ui[q] : n_users + ii[q - nq];

    const float* embrow = (node < n_users) ? &uw[(size_t)node * D]
                                           : &iw[(size_t)(node - n_users) * D];
    float4 e0 = ((const float4*)embrow)[lane8 * 2];
    float4 e1 = ((const float4*)embrow)[lane8 * 2 + 1];
    uint4 xa = bufA[(size_t)node * 8 + lane8];
    uint4 xb = bufB[(size_t)node * 8 + lane8];
    float a0 = e0.x + bf_lo(xa.x) + bf_lo(xb.x);
    float a1 = e0.y + bf_hi(xa.x) + bf_hi(xb.x);
    float a2 = e0.z + bf_lo(xa.y) + bf_lo(xb.y);
    float a3 = e0.w + bf_hi(xa.y) + bf_hi(xb.y);
    float a4 = e1.x + bf_lo(xa.z) + bf_lo(xb.z);
    float a5 = e1.y + bf_hi(xa.z) + bf_hi(xb.z);
    float a6 = e1.z + bf_lo(xa.w) + bf_lo(xb.w);
    float a7 = e1.w + bf_hi(xa.w) + bf_hi(xb.w);

    int s = rstart[node], dg = cnt[node];
    int j = 0;
    for (; j + 1 < dg; j += 2) {
        int2 ed0 = cedge[s + j], ed1 = cedge[s + j + 1];
        uint4 x0 = bufB[(size_t)ed0.x * 8 + lane8];
        uint4 x1 = bufB[(size_t)ed1.x * 8 + lane8];
        float v0 = __int_as_float(ed0.y), v1 = __int_as_float(ed1.y);
        a0 += v0 * bf_lo(x0.x) + v1 * bf_lo(x1.x);
        a1 += v0 * bf_hi(x0.x) + v1 * bf_hi(x1.x);
        a2 += v0 * bf_lo(x0.y) + v1 * bf_lo(x1.y);
        a3 += v0 * bf_hi(x0.y) + v1 * bf_hi(x1.y);
        a4 += v0 * bf_lo(x0.z) + v1 * bf_lo(x1.z);
        a5 += v0 * bf_hi(x0.z) + v1 * bf_hi(x1.z);
        a6 += v0 * bf_lo(x0.w) + v1 * bf_lo(x1.w);
        a7 += v0 * bf_hi(x0.w) + v1 * bf_hi(x1.w);
    }
    if (j < dg) {
        int2 ed0 = cedge[s + j];
        uint4 x0 = bufB[(size_t)ed0.x * 8 + lane8];
        float v0 = __int_as_float(ed0.y);
        a0 += v0 * bf_lo(x0.x); a1 += v0 * bf_hi(x0.x);
        a2 += v0 * bf_lo(x0.y); a3 += v0 * bf_hi(x0.y);
        a4 += v0 * bf_lo(x0.z); a5 += v0 * bf_hi(x0.z);
        a6 += v0 * bf_lo(x0.w); a7 += v0 * bf_hi(x0.w);
    }
    float4 o0 = { a0 * scale, a1 * scale, a2 * scale, a3 * scale };
    float4 o1 = { a4 * scale, a5 * scale, a6 * scale, a7 * scale };
    ((float4*)&out[(size_t)q * D])[lane8 * 2] = o0;
    ((float4*)&out[(size_t)q * D])[lane8 * 2 + 1] = o1;
}

// ===================== fallback (atomic path, f32) ==========================

__global__ __launch_bounds__(256) void k_gather_init(
    const float* __restrict__ uw, const float* __restrict__ iw,
    const int* __restrict__ ui, const int* __restrict__ ii,
    float* __restrict__ out, int nq)
{
    int t = blockIdx.x * 256 + threadIdx.x;
    int total = nq * D;
    if (t < total) {
        int q = t >> 6, d = t & 63;
        out[t] = uw[ui[q] * D + d];
    } else if (t < 2 * total) {
        int u = t - total;
        int q = u >> 6, d = u & 63;
        out[t] = iw[ii[q] * D + d];
    }
}

__global__ __launch_bounds__(256) void k_gather_acc(
    const float* __restrict__ src,
    const int* __restrict__ ui, const int* __restrict__ ii,
    int n_users, float* __restrict__ out, int nq, float scale)
{
    int t = blockIdx.x * 256 + threadIdx.x;
    int total = nq * D;
    if (t < total) {
        int q = t >> 6, d = t & 63;
        out[t] = (out[t] + src[ui[q] * D + d]) * scale;
    } else if (t < 2 * total) {
        int u = t - total;
        int q = u >> 6, d = u & 63;
        out[t] = (out[t] + src[(n_users + ii[q]) * D + d]) * scale;
    }
}

__global__ __launch_bounds__(256) void k_spmm_l0(
    const float* __restrict__ vals, const int* __restrict__ rows,
    const int* __restrict__ cols,
    const float* __restrict__ uw, const float* __restrict__ iw, int n_users,
    float* __restrict__ dst, int n_edges)
{
    int total = n_edges * D;
    int stride = gridDim.x * 256;
    for (int t = blockIdx.x * 256 + threadIdx.x; t < total; t += stride) {
        int e = t >> 6, d = t & 63;
        float v = vals[e];
        int c = cols[e], r = rows[e];
        float x = (c < n_users) ? uw[c * D + d] : iw[(c - n_users) * D + d];
        atomicAdd(dst + r * D + d, v * x);
    }
}

__global__ __launch_bounds__(256) void k_spmm(
    const float* __restrict__ vals, const int* __restrict__ rows,
    const int* __restrict__ cols,
    const float* __restrict__ src, float* __restrict__ dst, int n_edges)
{
    int total = n_edges * D;
    int stride = gridDim.x * 256;
    for (int t = blockIdx.x * 256 + threadIdx.x; t < total; t += stride) {
        int e = t >> 6, d = t & 63;
        float v = vals[e];
        int c = cols[e], r = rows[e];
        atomicAdd(dst + r * D + d, v * src[c * D + d]);
    }
}

// ============================================================================

extern "C" void kernel_launch(void* const* d_in, const int* in_sizes, int n_in,
                              void* d_out, int out_size, void* d_ws, size_t ws_size,
                              hipStream_t stream) {
    const float* uw   = (const float*)d_in[0];
    const float* iw   = (const float*)d_in[1];
    const float* vals = (const float*)d_in[2];
    const int*   rows = (const int*)d_in[3];
    const int*   cols = (const int*)d_in[4];
    const int*   ui   = (const int*)d_in[5];
    const int*   ii   = (const int*)d_in[6];
    float* out = (float*)d_out;

    const int n_users = in_sizes[0] / D;
    const int n_items = in_sizes[1] / D;
    const int n_nodes = n_users + n_items;
    const int n_edges = in_sizes[2];
    const int nq      = in_sizes[5];

    const int nb = (n_nodes + RB - 1) / RB;

    // ---- workspace carve ----
    size_t off = 0;
    int* cnt     = (int*)((char*)d_ws + off); off += (size_t)n_nodes * 4;
    int* rstart  = (int*)((char*)d_ws + off); off += (size_t)n_nodes * 4;
    int* bstart  = (int*)((char*)d_ws + off); off += 4096 * 4;
    int* bcnt    = (int*)((char*)d_ws + off); off += 4096 * 4;
    int* bktFill = (int*)((char*)d_ws + off); off += 4096 * 4;
    unsigned char* flag = (unsigned char*)((char*)d_ws + off);
    off += ((size_t)n_nodes + 255) & ~(size_t)255;
    size_t big = off;

    // csr path: bf16 tables + edge arrays
    size_t coff = big;
    unsigned* embB  = (unsigned*)((char*)d_ws + coff); coff += (size_t)n_nodes * D * 2;
    unsigned* bufAh = (unsigned*)((char*)d_ws + coff); coff += (size_t)n_nodes * D * 2;
    unsigned* bufBh = (unsigned*)((char*)d_ws + coff); coff += (size_t)n_nodes * D * 2;
    int2* cedge   = (int2*)((char*)d_ws + coff); coff += (size_t)n_edges * 8;
    int2* staging = (int2*)((char*)d_ws + coff); coff += (size_t)n_edges * 8;

    // fallback path: two f32 node buffers
    size_t foff = big;
    float* bufA = (float*)((char*)d_ws + foff); foff += (size_t)n_nodes * D * 4;
    float* bufB = (float*)((char*)d_ws + foff); foff += (size_t)n_nodes * D * 4;

    const int gq = (2 * nq * D + 255) / 256;
    const bool csr_ok = (coff <= ws_size) && (nb < 1024) &&
                        (nb + 1 <= NBMAX) && (n_nodes < (1 << COL_BITS));

    if (csr_ok) {
        // ---- bf16 conversion of embedding tables (one streamed pass) ----
        k_tobf2<<<2048, 256, 0, stream>>>(uw, iw, embB,
                                          n_users * (D / 2), n_items * (D / 2));

        // ---- CSR build (bucket histogram -> scan -> partition -> fused place) ----
        hipMemsetAsync(bcnt, 0, 4096 * 4, stream);
        hipMemsetAsync(flag, 0, (size_t)n_nodes, stream);
        k_bcount<<<(n_edges + TILE - 1) / TILE, 256, 0, stream>>>(rows, bcnt, n_edges, nb);
        k_bscan<<<1, 1024, 0, stream>>>(bcnt, bstart, bktFill, nb);
        k_binpart<<<(n_edges + TILE - 1) / TILE, 256, 0, stream>>>(
            vals, rows, cols, bktFill, staging, n_edges, nb);
        k_place3<<<nb, 256, 0, stream>>>(bstart, staging, rstart, cnt,
                                         cedge, n_nodes, n_edges);
        k_mark<<<(2 * nq + 255) / 256, 256, 0, stream>>>(
            rstart, cnt, cedge, ui, ii, n_users, flag, nq);

        const int gs32 = (n_nodes + 31) / 32;
        const int gq32 = (2 * nq + 31) / 32;
        // ---- layer 1: embB -> bufAh (all rows) ----
        k_spmm_bf8<<<gs32, 256, 0, stream>>>(rstart, cnt, cedge, (const uint4*)embB,
                                             (uint4*)bufAh, n_nodes, nullptr);
        // ---- layer 2: bufAh -> bufBh (marked rows only) ----
        k_spmm_bf8<<<gs32, 256, 0, stream>>>(rstart, cnt, cedge, (const uint4*)bufAh,
                                             (uint4*)bufBh, n_nodes, flag);
        // ---- fused epilogue: layers 0..3 per query ----
        k_final_all<<<gq32, 256, 0, stream>>>(rstart, cnt, cedge, uw, iw,
                                              (const uint4*)bufAh, (const uint4*)bufBh,
                                              ui, ii, n_users, out, nq, 0.25f);
    } else {
        // ---- fallback: atomic f32 path ----
        hipMemsetAsync(bufA, 0, 2 * (size_t)n_nodes * D * 4, stream);
        const int gs = 8192;
        k_gather_init<<<gq, 256, 0, stream>>>(uw, iw, ui, ii, out, nq);
        k_spmm_l0<<<gs, 256, 0, stream>>>(vals, rows, cols, uw, iw, n_users, bufA, n_edges);
        k_gather_acc<<<gq, 256, 0, stream>>>(bufA, ui, ii, n_users, out, nq, 1.0f);
        k_spmm<<<gs, 256, 0, stream>>>(vals, rows, cols, bufA, bufB, n_edges);
        k_gather_acc<<<gq, 256, 0, stream>>>(bufB, ui, ii, n_users, out, nq, 1.0f);
        hipMemsetAsync(bufA, 0, (size_t)n_nodes * D * 4, stream);
        k_spmm<<<gs, 256, 0, stream>>>(vals, rows, cols, bufB, bufA, n_edges);
        k_gather_acc<<<gq, 256, 0, stream>>>(bufA, ui, ii, n_users, out, nq, 0.25f);
    }
}